// Round 8
// baseline (620.512 us; speedup 1.0000x reference)
//
#include <hip/hip_runtime.h>

// SoftMorphology soft-skeleton: columns-in-registers, shuffle-based stencil.
// Round-8: same verified algorithm as rounds 4-7. Rounds 4-7 root cause:
// f[] was runtime-indexed in the IR seen by the FIRST SROA pass (constant
// indices only appeared after loop-unroll, which runs later), so the array
// stayed in scratch: VGPR_Count pinned at 128 and WRITE_SIZE inflated
// (627 MB vs 128 MB ideal) every round, regardless of #pragma unroll or
// per-stage templates.
// Fix: NO loops over f[]/sk[] at all -- template recursion (Unroll<I,N>)
// makes every array index a constexpr template parameter in the source, so
// the very first SROA splits f[] into 22 float4 SSA values. All row-range
// conditions are if constexpr.
//
// Layout: 256-thread blocks = 4 independent waves, each owning its own
// RV=8-row y-strip (no LDS, no barriers). Wave owns 256 cols (4/lane,
// float4), R rows in registers. Vertical neighbors register-local;
// horizontal = 2 shuffles/row. grid.x=5 column windows (write cols
// 208,208,208,208,192), left halo 8 >= STAGES+1=7; region-edge clamped
// reads contaminate <=1 col/stage inward, halo keeps it dead.
//
// Two launches: STAGES=6 (init + iters 1..5, writes E6+skel) and STAGES=5
// (iters 6..10, writes skel). R = RV+2*(STAGES+1) = 22 / 20 rows/lane.
//
// Per stage one in-place ascending pass: at step i,
//   e = erode(old f[i-1..i+1]) -> f[i-1] (window shifts up 1/stage);
//   h0 = hmax3(e) rolling (h2,h1,h0 = new rows i-3,i-2,i-1);
//   skel row k=i-2-(HALO-T): dilate = vmax3(h2,h1,h0); A_{t-1} = pm1.
//
// Borders: staged loads clamp row/col (replicate guards). EROSION absorbs
// replicate guards (center term dominates the min; induction per stage).
// DILATE needs exact extension: per-lane overrides at image cols 0/1023,
// h-row swap at image rows 0/1023.

#define W 1024
#define H 1024
#define NBATCH 16
#define RV 8

template <int I>
struct IC {
  static constexpr int v = I;
};

// Compile-time for: fn(IC<I>{}) for I in [I, N)
template <int I, int N>
struct Unroll {
  template <class F>
  __device__ __forceinline__ static void run(F&& fn) {
    fn(IC<I>{});
    Unroll<I + 1, N>::run(static_cast<F&&>(fn));
  }
};
template <int N>
struct Unroll<N, N> {
  template <class F>
  __device__ __forceinline__ static void run(F&&) {}
};

__device__ __forceinline__ float min3f(float a, float b, float c) {
  return fminf(fminf(a, b), c);
}
__device__ __forceinline__ float max3f(float a, float b, float c) {
  return fmaxf(fmaxf(a, b), c);
}

// One erosion stage T (1-based) of a launch with STAGES stages total.
template <int T, int STAGES, bool FIRST, int R>
__device__ __forceinline__ void do_stage(float4 (&f)[R], float4 (&sk)[RV],
                                         const bool mL, const bool mR,
                                         const bool top, const bool bot) {
  constexpr int HALO = STAGES + 1;
  constexpr int V = R - 2 * (T - 1);  // valid rows at stage entry
  float4 pm1 = f[0];
  float4 h0 = {0, 0, 0, 0}, h1 = {0, 0, 0, 0}, h2 = {0, 0, 0, 0};
  Unroll<1, V - 1>::run([&](auto t) {
    constexpr int i = decltype(t)::v;
    const float4 cur = f[i];
    const float4 nxt = f[i + 1];
    // erode: vertical min3 then cross with horizontal neighbors
    float4 e;
    const float vmx = min3f(pm1.x, cur.x, nxt.x);
    const float vmy = min3f(pm1.y, cur.y, nxt.y);
    const float vmz = min3f(pm1.z, cur.z, nxt.z);
    const float vmw = min3f(pm1.w, cur.w, nxt.w);
    float Lin = __shfl_up(cur.w, 1, 64);
    if (mL) Lin = cur.x;                  // image col 0: ext == center
    float Rin = __shfl_down(cur.x, 1, 64);
    if (mR) Rin = cur.w;                  // image col 1023
    e.x = min3f(vmx, Lin, cur.y);
    e.y = min3f(vmy, cur.x, cur.z);
    e.z = min3f(vmz, cur.y, cur.w);
    e.w = min3f(vmw, cur.z, Rin);
    f[i - 1] = e;                         // in-place, window shifts up

    // h = hmax3(e) for new-row m=i-1, needed for m in [jlo-1, jhi+1]
    if constexpr (i >= HALO - T && i <= HALO - T + RV + 1) {
      float Lh = __shfl_up(e.w, 1, 64);
      if (mL) Lh = e.x;
      float Rh = __shfl_down(e.x, 1, 64);
      if (mR) Rh = e.w;
      h0.x = max3f(Lh, e.x, e.y);
      h0.y = max3f(e.x, e.y, e.z);
      h0.z = max3f(e.y, e.z, e.w);
      h0.w = max3f(e.z, e.w, Rh);
    }
    // update for skel row k: new-idx center j=i-2; pm1 == A_{t-1} there
    if constexpr (i >= HALO - T + 2 && i <= HALO - T + RV + 1) {
      constexpr int k = i - 2 - (HALO - T);
      float4 ha = h2, hb = h0;
      if constexpr (k == 0) {
        if (top) ha = h1;                 // image row 0: ext == center
      }
      if constexpr (k == RV - 1) {
        if (bot) hb = h1;                 // image row 1023
      }
      float4 dd, dl;
      dd.x = max3f(ha.x, h1.x, hb.x);
      dd.y = max3f(ha.y, h1.y, hb.y);
      dd.z = max3f(ha.z, h1.z, hb.z);
      dd.w = max3f(ha.w, h1.w, hb.w);
      dl.x = fmaxf(pm1.x - dd.x, 0.f);
      dl.y = fmaxf(pm1.y - dd.y, 0.f);
      dl.z = fmaxf(pm1.z - dd.z, 0.f);
      dl.w = fmaxf(pm1.w - dd.w, 0.f);
      if constexpr (FIRST && T == 1) {
        sk[k] = dl;
      } else {
        sk[k].x += fmaxf(dl.x - sk[k].x * dl.x, 0.f);
        sk[k].y += fmaxf(dl.y - sk[k].y * dl.y, 0.f);
        sk[k].z += fmaxf(dl.z - sk[k].z * dl.z, 0.f);
        sk[k].w += fmaxf(dl.w - sk[k].w * dl.w, 0.f);
      }
    }
    h2 = h1;
    h1 = h0;
    pm1 = cur;
  });
}

template <int STAGES, bool FIRST, bool EOUT>
__global__ __launch_bounds__(256, 2) void skel_pass(
    const float* __restrict__ in,   // E_s  (img when FIRST)
    float* __restrict__ e_out,      // E_{s+STAGES} out (EOUT only)
    float* __restrict__ skel) {
  constexpr int HALO = STAGES + 1;
  constexpr int R = RV + 2 * HALO;

  const int l = threadIdx.x & 63;           // lane
  const int wid = threadIdx.x >> 6;         // wave 0..3 -> y sub-strip
  const int w = blockIdx.x;                 // 0..4 column windows
  const int y0 = (blockIdx.y * 4 + wid) * RV;
  const size_t base = (size_t)blockIdx.z * (size_t)(W * H);

  const int rx = 208 * w - 8 + 4 * l;       // lane's col start (may be OOB)
  const int cq = min(max(rx, 0), W - 4);    // clamped load col
  const bool mL = (rx == 0);                // lane's c0 is image col 0
  const bool mR = (rx == W - 4);            // lane's c3 is image col 1023
  const bool top = (y0 == 0);
  const bool bot = (y0 + RV == H);
  const int wend = min(208 * (w + 1), W);
  const bool wr = (rx >= 208 * w) && (rx < wend);

  // ---- stage input rows (row/col clamped); constexpr indices only ----
  float4 f[R];
  Unroll<0, R>::run([&](auto t) {
    constexpr int i = decltype(t)::v;
    const int gy = min(max(y0 - HALO + i, 0), H - 1);
    f[i] = *(const float4*)(in + base + (size_t)gy * W + cq);
  });

  float4 sk[RV];
  if (!FIRST) {
    Unroll<0, RV>::run([&](auto t) {
      constexpr int k = decltype(t)::v;
      sk[k] = *(const float4*)(skel + base + (size_t)(y0 + k) * W + cq);
    });
  }

  // ---- stages, each with constexpr trip counts ----
  do_stage<1, STAGES, FIRST>(f, sk, mL, mR, top, bot);
  do_stage<2, STAGES, FIRST>(f, sk, mL, mR, top, bot);
  do_stage<3, STAGES, FIRST>(f, sk, mL, mR, top, bot);
  do_stage<4, STAGES, FIRST>(f, sk, mL, mR, top, bot);
  if constexpr (STAGES >= 5) do_stage<5, STAGES, FIRST>(f, sk, mL, mR, top, bot);
  if constexpr (STAGES >= 6) do_stage<6, STAGES, FIRST>(f, sk, mL, mR, top, bot);

  // ---- stores: write lanes only (disjoint quad-aligned windows) ----
  if (wr) {
    Unroll<0, RV>::run([&](auto t) {
      constexpr int k = decltype(t)::v;
      *(float4*)(skel + base + (size_t)(y0 + k) * W + rx) = sk[k];
    });
    if constexpr (EOUT) {
      // after STAGES stages, row y0+k sits at f[HALO - STAGES + k] = f[1+k]
      Unroll<0, RV>::run([&](auto t) {
        constexpr int k = decltype(t)::v;
        *(float4*)(e_out + base + (size_t)(y0 + k) * W + rx) = f[1 + k];
      });
    }
  }
}

extern "C" void kernel_launch(void* const* d_in, const int* in_sizes, int n_in,
                              void* d_out, int out_size, void* d_ws,
                              size_t ws_size, hipStream_t stream) {
  const float* img = (const float*)d_in[0];
  float* skel = (float*)d_out;
  float* E = (float*)d_ws;  // 64 MiB: E6 between the two launches

  dim3 grid(5, H / (4 * RV), NBATCH);  // 5 x 32 x 16 = 2560 blocks
  // L1: k=0 init + iters 1..5; reads img, writes E6 + skel.
  skel_pass<6, true, true><<<grid, 256, 0, stream>>>(img, E, skel);
  // L2: iters 6..10; reads E6 + skel, writes skel.
  skel_pass<5, false, false><<<grid, 256, 0, stream>>>(E, nullptr, skel);
}

// Round 10
// 214.395 us; speedup vs baseline: 2.8942x; 2.8942x over previous
//
#include <hip/hip_runtime.h>
#include <hip/hip_fp16.h>

// SoftMorphology soft-skeleton: columns-in-registers shuffle stencil, f16.
// Rounds 4-8 lesson: ANY array (runtime loop, unrolled, or template-recursed)
// went to scratch (VGPR pinned 128, WRITE_SIZE inflated by 0.5-1.2 GB).
// Round-9/10 design: ZERO arrays. All state is named scalars, and the eroded
// field is packed f16 (half2 per reg) so total demand ~110 VGPR < 128.
//   - erode/dilate are min/max (selection): f16 result == f16(exact result),
//     monotone; only input-quantization error (<=2^-11) enters each delta.
//   - skel kept f32 as q = 1-s; update s+=relu(d-s*d) == q*=(1-d) exactly
//     (relu is a no-op for inputs in [0,1]); store s = 1-q.
// Round-10 fix: ROCm 7.2 hip_fp16.h lacks __hmin2/__hmax2 -> emit
// v_pk_min_f16 / v_pk_max_f16 (gfx950 VOP3P) via non-volatile inline asm.
// Two launches: S=6 (init + iters 1..5, writes E6(f16)+skel), S=5
// (iters 6..10). R = RV + 2*(S+1) = 22 / 20 packed rows, RV=8.
// Per wave: 256 cols (4/lane), rows in regs; horizontal = 2 shuffles/row +
// bit-combines on packed halves. 5 column windows (write cols 208x4+192),
// halo 8 >= S+1. Borders: clamped loads = replicate guards, absorbed by
// erode (verified rounds 4-8); dilate gets exact extension via mL/mR lane
// overrides and top/bot h-row swaps.

#define W 1024
#define H 1024
#define NBATCH 16
#define RV 8

__device__ __forceinline__ uint32_t HMIN2(uint32_t a, uint32_t b) {
  uint32_t d;
  asm("v_pk_min_f16 %0, %1, %2" : "=v"(d) : "v"(a), "v"(b));
  return d;
}
__device__ __forceinline__ uint32_t HMAX2(uint32_t a, uint32_t b) {
  uint32_t d;
  asm("v_pk_max_f16 %0, %1, %2" : "=v"(d) : "v"(a), "v"(b));
  return d;
}
__device__ __forceinline__ uint32_t PK(float x, float y) {
  __half2 h = __floats2half2_rn(x, y);
  return *(uint32_t*)&h;
}
__device__ __forceinline__ float CVTLO(uint32_t u) {
  uint16_t t = (uint16_t)(u & 0xffffu);
  __half h = *(__half*)&t;
  return __half2float(h);
}
__device__ __forceinline__ float CVTHI(uint32_t u) {
  uint16_t t = (uint16_t)(u >> 16);
  __half h = *(__half*)&t;
  return __half2float(h);
}

// One pipeline step: erode (row P <- min-cross of PM,C,N), rolling h-max,
// and skel-q update for row K. All indices are literal tokens.
#define STEP(P, C, N, DOH, DOU, K, INIT) {                                  \
  const uint32_t ca = F##C##a, cb = F##C##b;                                \
  const uint32_t na = F##N##a, nb = F##N##b;                                \
  const uint32_t vma = HMIN2(HMIN2(PMa, ca), na);                           \
  const uint32_t vmb = HMIN2(HMIN2(PMb, cb), nb);                           \
  const uint32_t t = (uint32_t)__shfl_up((int)cb, 1, 64);                   \
  const uint32_t r = (uint32_t)__shfl_down((int)ca, 1, 64);                 \
  const uint32_t m1 = mL ? (ca & 0xffffu) : (t >> 16);                      \
  const uint32_t r4 = mR ? (cb >> 16) : (r & 0xffffu);                      \
  const uint32_t sla = (ca >> 16) | (cb << 16);                             \
  const uint32_t slb = (cb >> 16) | (r4 << 16);                             \
  const uint32_t sra = m1 | (ca << 16);                                     \
  const uint32_t ea = HMIN2(vma, HMIN2(sra, sla));                          \
  const uint32_t eb = HMIN2(vmb, HMIN2(sla, slb));                          \
  if (DOH) {                                                                \
    const uint32_t te = (uint32_t)__shfl_up((int)eb, 1, 64);                \
    const uint32_t re = (uint32_t)__shfl_down((int)ea, 1, 64);              \
    const uint32_t em1 = mL ? (ea & 0xffffu) : (te >> 16);                  \
    const uint32_t er4 = mR ? (eb >> 16) : (re & 0xffffu);                  \
    const uint32_t esla = (ea >> 16) | (eb << 16);                          \
    const uint32_t eslb = (eb >> 16) | (er4 << 16);                         \
    const uint32_t esra = em1 | (ea << 16);                                 \
    const uint32_t hca = HMAX2(ea, HMAX2(esra, esla));                      \
    const uint32_t hcb = HMAX2(eb, HMAX2(esla, eslb));                      \
    if (DOU) {                                                              \
      uint32_t haa = h2a, hab = h2b, hba = hca, hbb = hcb;                  \
      if (K == 0 && top) { haa = h1a; hab = h1b; }                          \
      if (K == RV - 1 && bot) { hba = h1a; hbb = h1b; }                     \
      const uint32_t dda = HMAX2(HMAX2(haa, h1a), hba);                     \
      const uint32_t ddb = HMAX2(HMAX2(hab, h1b), hbb);                     \
      float d0 = CVTLO(dda) - CVTLO(PMa) + 1.0f;                            \
      float d1 = CVTHI(dda) - CVTHI(PMa) + 1.0f;                            \
      float d2 = CVTLO(ddb) - CVTLO(PMb) + 1.0f;                            \
      float d3 = CVTHI(ddb) - CVTHI(PMb) + 1.0f;                            \
      d0 = fminf(d0, 1.0f); d1 = fminf(d1, 1.0f);                           \
      d2 = fminf(d2, 1.0f); d3 = fminf(d3, 1.0f);                           \
      if (INIT) { Q##K.x = d0; Q##K.y = d1; Q##K.z = d2; Q##K.w = d3; }     \
      else { Q##K.x *= d0; Q##K.y *= d1; Q##K.z *= d2; Q##K.w *= d3; }      \
    }                                                                       \
    h2a = h1a; h2b = h1b; h1a = hca; h1b = hcb;                             \
  }                                                                         \
  F##P##a = ea; F##P##b = eb;                                               \
  PMa = ca; PMb = cb;                                                       \
}

#define STAGE_BEGIN uint32_t PMa = F0a, PMb = F0b,                          \
    h1a = 0, h1b = 0, h2a = 0, h2b = 0;

// Stage bodies by valid-row count V. H window [HALO-T, HALO-T+RV+1],
// U window [HALO-T+2, HALO-T+RV+1], K = i-2-(HALO-T).
#define S_V22(INIT) { STAGE_BEGIN                                           \
  STEP(0,1,2,0,0,0,INIT)  STEP(1,2,3,0,0,0,INIT)  STEP(2,3,4,0,0,0,INIT)    \
  STEP(3,4,5,0,0,0,INIT)  STEP(4,5,6,0,0,0,INIT)                            \
  STEP(5,6,7,1,0,0,INIT)  STEP(6,7,8,1,0,0,INIT)                            \
  STEP(7,8,9,1,1,0,INIT)  STEP(8,9,10,1,1,1,INIT) STEP(9,10,11,1,1,2,INIT)  \
  STEP(10,11,12,1,1,3,INIT) STEP(11,12,13,1,1,4,INIT)                       \
  STEP(12,13,14,1,1,5,INIT) STEP(13,14,15,1,1,6,INIT)                       \
  STEP(14,15,16,1,1,7,INIT)                                                 \
  STEP(15,16,17,0,0,0,INIT) STEP(16,17,18,0,0,0,INIT)                       \
  STEP(17,18,19,0,0,0,INIT) STEP(18,19,20,0,0,0,INIT)                       \
  STEP(19,20,21,0,0,0,INIT) }

#define S_V20 { STAGE_BEGIN                                                 \
  STEP(0,1,2,0,0,0,0)   STEP(1,2,3,0,0,0,0)   STEP(2,3,4,0,0,0,0)           \
  STEP(3,4,5,0,0,0,0)                                                       \
  STEP(4,5,6,1,0,0,0)   STEP(5,6,7,1,0,0,0)                                 \
  STEP(6,7,8,1,1,0,0)   STEP(7,8,9,1,1,1,0)   STEP(8,9,10,1,1,2,0)          \
  STEP(9,10,11,1,1,3,0) STEP(10,11,12,1,1,4,0) STEP(11,12,13,1,1,5,0)       \
  STEP(12,13,14,1,1,6,0) STEP(13,14,15,1,1,7,0)                             \
  STEP(14,15,16,0,0,0,0) STEP(15,16,17,0,0,0,0) STEP(16,17,18,0,0,0,0)      \
  STEP(17,18,19,0,0,0,0) }

#define S_V18 { STAGE_BEGIN                                                 \
  STEP(0,1,2,0,0,0,0)   STEP(1,2,3,0,0,0,0)   STEP(2,3,4,0,0,0,0)           \
  STEP(3,4,5,1,0,0,0)   STEP(4,5,6,1,0,0,0)                                 \
  STEP(5,6,7,1,1,0,0)   STEP(6,7,8,1,1,1,0)   STEP(7,8,9,1,1,2,0)           \
  STEP(8,9,10,1,1,3,0)  STEP(9,10,11,1,1,4,0) STEP(10,11,12,1,1,5,0)        \
  STEP(11,12,13,1,1,6,0) STEP(12,13,14,1,1,7,0)                             \
  STEP(13,14,15,0,0,0,0) STEP(14,15,16,0,0,0,0) STEP(15,16,17,0,0,0,0) }

#define S_V16 { STAGE_BEGIN                                                 \
  STEP(0,1,2,0,0,0,0)   STEP(1,2,3,0,0,0,0)                                 \
  STEP(2,3,4,1,0,0,0)   STEP(3,4,5,1,0,0,0)                                 \
  STEP(4,5,6,1,1,0,0)   STEP(5,6,7,1,1,1,0)   STEP(6,7,8,1,1,2,0)           \
  STEP(7,8,9,1,1,3,0)   STEP(8,9,10,1,1,4,0)  STEP(9,10,11,1,1,5,0)         \
  STEP(10,11,12,1,1,6,0) STEP(11,12,13,1,1,7,0)                             \
  STEP(12,13,14,0,0,0,0) STEP(13,14,15,0,0,0,0) }

#define S_V14 { STAGE_BEGIN                                                 \
  STEP(0,1,2,0,0,0,0)                                                       \
  STEP(1,2,3,1,0,0,0)   STEP(2,3,4,1,0,0,0)                                 \
  STEP(3,4,5,1,1,0,0)   STEP(4,5,6,1,1,1,0)   STEP(5,6,7,1,1,2,0)           \
  STEP(6,7,8,1,1,3,0)   STEP(7,8,9,1,1,4,0)   STEP(8,9,10,1,1,5,0)          \
  STEP(9,10,11,1,1,6,0) STEP(10,11,12,1,1,7,0)                              \
  STEP(11,12,13,0,0,0,0) }

#define S_V12 { STAGE_BEGIN                                                 \
  STEP(0,1,2,1,0,0,0)   STEP(1,2,3,1,0,0,0)                                 \
  STEP(2,3,4,1,1,0,0)   STEP(3,4,5,1,1,1,0)   STEP(4,5,6,1,1,2,0)           \
  STEP(5,6,7,1,1,3,0)   STEP(6,7,8,1,1,4,0)   STEP(7,8,9,1,1,5,0)           \
  STEP(8,9,10,1,1,6,0)  STEP(9,10,11,1,1,7,0) }

#define DECLF(i) uint32_t F##i##a, F##i##b;

#define COMMON_SETUP                                                        \
  const int l = threadIdx.x & 63;                                           \
  const int wid = threadIdx.x >> 6;                                         \
  const int w = blockIdx.x;                                                 \
  const int y0 = (blockIdx.y * 4 + wid) * RV;                               \
  const size_t base = (size_t)blockIdx.z * (size_t)(W * H);                 \
  const int rx = 208 * w - 8 + 4 * l;                                       \
  const int cq = min(max(rx, 0), W - 4);                                    \
  const bool mL = (rx == 0);                                                \
  const bool mR = (rx == W - 4);                                            \
  const bool top = (y0 == 0);                                               \
  const bool bot = (y0 + RV == H);                                          \
  const int wend = min(208 * (w + 1), W);                                   \
  const bool wr = (rx >= 208 * w) && (rx < wend);

// Launch 1: stages 1..6 (skel init + iters 1..5); reads img f32, writes
// E6 (f16 packed) + skel.
__global__ __launch_bounds__(256) void skel6(const float* __restrict__ in,
                                             uint16_t* __restrict__ e16,
                                             float* __restrict__ skel) {
  COMMON_SETUP
  DECLF(0) DECLF(1) DECLF(2) DECLF(3) DECLF(4) DECLF(5) DECLF(6) DECLF(7)
  DECLF(8) DECLF(9) DECLF(10) DECLF(11) DECLF(12) DECLF(13) DECLF(14)
  DECLF(15) DECLF(16) DECLF(17) DECLF(18) DECLF(19) DECLF(20) DECLF(21)
  float4 Q0, Q1, Q2, Q3, Q4, Q5, Q6, Q7;

#define LOADROW1(i) {                                                       \
    const int gy = min(max(y0 - 7 + i, 0), H - 1);                          \
    const float4 v = *(const float4*)(in + base + (size_t)gy * W + cq);     \
    F##i##a = PK(v.x, v.y); F##i##b = PK(v.z, v.w); }
  LOADROW1(0) LOADROW1(1) LOADROW1(2) LOADROW1(3) LOADROW1(4) LOADROW1(5)
  LOADROW1(6) LOADROW1(7) LOADROW1(8) LOADROW1(9) LOADROW1(10) LOADROW1(11)
  LOADROW1(12) LOADROW1(13) LOADROW1(14) LOADROW1(15) LOADROW1(16)
  LOADROW1(17) LOADROW1(18) LOADROW1(19) LOADROW1(20) LOADROW1(21)
#undef LOADROW1

  S_V22(1) S_V20 S_V18 S_V16 S_V14 S_V12

  if (wr) {
#define STOREQ(k) {                                                         \
      float4 s;                                                             \
      s.x = 1.0f - Q##k.x; s.y = 1.0f - Q##k.y;                             \
      s.z = 1.0f - Q##k.z; s.w = 1.0f - Q##k.w;                             \
      *(float4*)(skel + base + (size_t)(y0 + k) * W + rx) = s; }
    STOREQ(0) STOREQ(1) STOREQ(2) STOREQ(3)
    STOREQ(4) STOREQ(5) STOREQ(6) STOREQ(7)
#undef STOREQ
    // E6 rows y0+k live in F(1+k) after 6 window shifts.
#define STOREE(k, j) {                                                      \
      *(uint2*)(e16 + base + (size_t)(y0 + k) * W + rx) =                   \
          make_uint2(F##j##a, F##j##b); }
    STOREE(0, 1) STOREE(1, 2) STOREE(2, 3) STOREE(3, 4)
    STOREE(4, 5) STOREE(5, 6) STOREE(6, 7) STOREE(7, 8)
#undef STOREE
  }
}

// Launch 2: stages 7..11 (iters 6..10); reads E6 (f16) + skel, writes skel.
__global__ __launch_bounds__(256) void skel5(const uint16_t* __restrict__ e16,
                                             float* __restrict__ skel) {
  COMMON_SETUP
  DECLF(0) DECLF(1) DECLF(2) DECLF(3) DECLF(4) DECLF(5) DECLF(6) DECLF(7)
  DECLF(8) DECLF(9) DECLF(10) DECLF(11) DECLF(12) DECLF(13) DECLF(14)
  DECLF(15) DECLF(16) DECLF(17) DECLF(18) DECLF(19)
  float4 Q0, Q1, Q2, Q3, Q4, Q5, Q6, Q7;

#define LOADROW2(i) {                                                       \
    const int gy = min(max(y0 - 6 + i, 0), H - 1);                          \
    const uint2 v = *(const uint2*)(e16 + base + (size_t)gy * W + cq);      \
    F##i##a = v.x; F##i##b = v.y; }
  LOADROW2(0) LOADROW2(1) LOADROW2(2) LOADROW2(3) LOADROW2(4) LOADROW2(5)
  LOADROW2(6) LOADROW2(7) LOADROW2(8) LOADROW2(9) LOADROW2(10) LOADROW2(11)
  LOADROW2(12) LOADROW2(13) LOADROW2(14) LOADROW2(15) LOADROW2(16)
  LOADROW2(17) LOADROW2(18) LOADROW2(19)
#undef LOADROW2

#define LOADQ(k) {                                                          \
    const float4 s = *(const float4*)(skel + base + (size_t)(y0 + k) * W + cq); \
    Q##k.x = 1.0f - s.x; Q##k.y = 1.0f - s.y;                               \
    Q##k.z = 1.0f - s.z; Q##k.w = 1.0f - s.w; }
  LOADQ(0) LOADQ(1) LOADQ(2) LOADQ(3) LOADQ(4) LOADQ(5) LOADQ(6) LOADQ(7)
#undef LOADQ

  S_V20 S_V18 S_V16 S_V14 S_V12

  if (wr) {
#define STOREQ(k) {                                                         \
      float4 s;                                                             \
      s.x = 1.0f - Q##k.x; s.y = 1.0f - Q##k.y;                             \
      s.z = 1.0f - Q##k.z; s.w = 1.0f - Q##k.w;                             \
      *(float4*)(skel + base + (size_t)(y0 + k) * W + rx) = s; }
    STOREQ(0) STOREQ(1) STOREQ(2) STOREQ(3)
    STOREQ(4) STOREQ(5) STOREQ(6) STOREQ(7)
#undef STOREQ
  }
}

extern "C" void kernel_launch(void* const* d_in, const int* in_sizes, int n_in,
                              void* d_out, int out_size, void* d_ws,
                              size_t ws_size, hipStream_t stream) {
  const float* img = (const float*)d_in[0];
  float* skel = (float*)d_out;
  uint16_t* E = (uint16_t*)d_ws;  // 32 MiB f16 E6 between launches

  dim3 grid(5, H / (4 * RV), NBATCH);  // 5 x 32 x 16 blocks, 256 thr
  skel6<<<grid, 256, 0, stream>>>(img, E, skel);
  skel5<<<grid, 256, 0, stream>>>(E, skel);
}

// Round 11
// 137.743 us; speedup vs baseline: 4.5048x; 1.5565x over previous
//
#include <hip/hip_runtime.h>
#include <hip/hip_fp16.h>

// SoftMorphology soft-skeleton: columns-in-registers shuffle stencil, f16.
// Round-10 proved: zero-array named-scalar state eliminates scratch
// (WRITE_SIZE exactly 96 MB, VGPR 148) but VGPR 148 > 128 costs half the
// wave slots -> occupancy 11%, VALUBusy 30%, latency-bound (skel6 184 us).
// Round-11: get under the 128-VGPR cliff (2 -> 4 waves/SIMD):
//   * RV 8 -> 4 (F rows 22 -> 18 packed, grid 2560 -> 5120 blocks)
//   * skel accumulator q = 1-s held as PACKED f16 (v_pk ops); update
//     q *= 1 - relu(pm - dd) is 4 pk ops vs ~20 f32/CVT ops -> less VALU.
// erode/dilate are min/max (selection) => f16-exact; only input
// quantization (2^-11) + 10 f16 RN muls enter the error: <~1e-2 << 1.98e-2.
// Two launches: skel6 = init + iters 1..5 (writes E6 f16 + skel),
// skel5 = iters 6..10. R = RV + 2*(S+1) = 18 / 16 packed rows.
// Per wave: 256 cols (4/lane as 2 half2), R rows in named regs; vertical
// neighbors register-local, horizontal = 2 shuffles/row; 5 column windows
// (write 208x4+192 cols), halo 8 >= S+1 = 7. Borders: clamped loads =
// replicate guards absorbed by erode (verified r5-r10); dilate gets exact
// extension via mL/mR lane overrides + top/bot h-row swaps.

#define W 1024
#define H 1024
#define NBATCH 16
#define RV 4

__device__ __forceinline__ uint32_t HMIN2(uint32_t a, uint32_t b) {
  uint32_t d;
  asm("v_pk_min_f16 %0, %1, %2" : "=v"(d) : "v"(a), "v"(b));
  return d;
}
__device__ __forceinline__ uint32_t HMAX2(uint32_t a, uint32_t b) {
  uint32_t d;
  asm("v_pk_max_f16 %0, %1, %2" : "=v"(d) : "v"(a), "v"(b));
  return d;
}
__device__ __forceinline__ uint32_t PKSUB(uint32_t a, uint32_t b) {
  uint32_t d;  // a - b (packed f16)
  asm("v_pk_add_f16 %0, %1, %2 neg_lo:[0,1] neg_hi:[0,1]"
      : "=v"(d) : "v"(a), "v"(b));
  return d;
}
__device__ __forceinline__ uint32_t PKMUL(uint32_t a, uint32_t b) {
  uint32_t d;
  asm("v_pk_mul_f16 %0, %1, %2" : "=v"(d) : "v"(a), "v"(b));
  return d;
}
__device__ __forceinline__ uint32_t PKRELU(uint32_t a) {
  uint32_t d;  // max(a, 0) packed
  asm("v_pk_max_f16 %0, %1, 0" : "=v"(d) : "v"(a));
  return d;
}
__device__ __forceinline__ uint32_t PK(float x, float y) {
  __half2 h = __floats2half2_rn(x, y);
  return *(uint32_t*)&h;
}
__device__ __forceinline__ float CVTLO(uint32_t u) {
  uint16_t t = (uint16_t)(u & 0xffffu);
  __half h = *(__half*)&t;
  return __half2float(h);
}
__device__ __forceinline__ float CVTHI(uint32_t u) {
  uint16_t t = (uint16_t)(u >> 16);
  __half h = *(__half*)&t;
  return __half2float(h);
}

// One pipeline step: erode (row P <- min-cross of PM,C,N), rolling h-max,
// packed-f16 skel-q update for row K. All indices literal tokens.
#define STEP(P, C, N, DOH, DOU, K, INIT) {                                  \
  const uint32_t ca = F##C##a, cb = F##C##b;                                \
  const uint32_t na = F##N##a, nb = F##N##b;                                \
  const uint32_t vma = HMIN2(HMIN2(PMa, ca), na);                           \
  const uint32_t vmb = HMIN2(HMIN2(PMb, cb), nb);                           \
  const uint32_t t = (uint32_t)__shfl_up((int)cb, 1, 64);                   \
  const uint32_t r = (uint32_t)__shfl_down((int)ca, 1, 64);                 \
  const uint32_t m1 = mL ? (ca & 0xffffu) : (t >> 16);                      \
  const uint32_t r4 = mR ? (cb >> 16) : (r & 0xffffu);                      \
  const uint32_t sla = (ca >> 16) | (cb << 16);                             \
  const uint32_t slb = (cb >> 16) | (r4 << 16);                             \
  const uint32_t sra = m1 | (ca << 16);                                     \
  const uint32_t ea = HMIN2(vma, HMIN2(sra, sla));                          \
  const uint32_t eb = HMIN2(vmb, HMIN2(sla, slb));                          \
  if (DOH) {                                                                \
    const uint32_t te = (uint32_t)__shfl_up((int)eb, 1, 64);                \
    const uint32_t re = (uint32_t)__shfl_down((int)ea, 1, 64);              \
    const uint32_t em1 = mL ? (ea & 0xffffu) : (te >> 16);                  \
    const uint32_t er4 = mR ? (eb >> 16) : (re & 0xffffu);                  \
    const uint32_t esla = (ea >> 16) | (eb << 16);                          \
    const uint32_t eslb = (eb >> 16) | (er4 << 16);                         \
    const uint32_t esra = em1 | (ea << 16);                                 \
    const uint32_t hca = HMAX2(ea, HMAX2(esra, esla));                      \
    const uint32_t hcb = HMAX2(eb, HMAX2(esla, eslb));                      \
    if (DOU) {                                                              \
      uint32_t haa = h2a, hab = h2b, hba = hca, hbb = hcb;                  \
      if (K == 0 && top) { haa = h1a; hab = h1b; }                          \
      if (K == RV - 1 && bot) { hba = h1a; hbb = h1b; }                     \
      const uint32_t dda = HMAX2(HMAX2(haa, h1a), hba);                     \
      const uint32_t ddb = HMAX2(HMAX2(hab, h1b), hbb);                     \
      const uint32_t fa = PKSUB(ONE2, PKRELU(PKSUB(PMa, dda)));             \
      const uint32_t fb = PKSUB(ONE2, PKRELU(PKSUB(PMb, ddb)));             \
      if (INIT) { Q##K##a = fa; Q##K##b = fb; }                             \
      else { Q##K##a = PKMUL(Q##K##a, fa); Q##K##b = PKMUL(Q##K##b, fb); }  \
    }                                                                       \
    h2a = h1a; h2b = h1b; h1a = hca; h1b = hcb;                             \
  }                                                                         \
  F##P##a = ea; F##P##b = eb;                                               \
  PMa = ca; PMb = cb;                                                       \
}

#define STAGE_BEGIN uint32_t PMa = F0a, PMb = F0b,                          \
    h1a = 0, h1b = 0, h2a = 0, h2b = 0;

// RV=4 stage bodies by valid-row count V; HT = HALO-T = (V-RV-2)/2.
// DOH window i in [HT, HT+RV+1], DOU i in [HT+2, HT+RV+1], K = i-2-HT.
#define S4_V18(INIT) { STAGE_BEGIN                                          \
  STEP(0,1,2,0,0,0,INIT)  STEP(1,2,3,0,0,0,INIT)  STEP(2,3,4,0,0,0,INIT)    \
  STEP(3,4,5,0,0,0,INIT)  STEP(4,5,6,0,0,0,INIT)                            \
  STEP(5,6,7,1,0,0,INIT)  STEP(6,7,8,1,0,0,INIT)                            \
  STEP(7,8,9,1,1,0,INIT)  STEP(8,9,10,1,1,1,INIT)                           \
  STEP(9,10,11,1,1,2,INIT) STEP(10,11,12,1,1,3,INIT)                        \
  STEP(11,12,13,0,0,0,INIT) STEP(12,13,14,0,0,0,INIT)                       \
  STEP(13,14,15,0,0,0,INIT) STEP(14,15,16,0,0,0,INIT)                       \
  STEP(15,16,17,0,0,0,INIT) }

#define S4_V16 { STAGE_BEGIN                                                \
  STEP(0,1,2,0,0,0,0)   STEP(1,2,3,0,0,0,0)   STEP(2,3,4,0,0,0,0)           \
  STEP(3,4,5,0,0,0,0)                                                       \
  STEP(4,5,6,1,0,0,0)   STEP(5,6,7,1,0,0,0)                                 \
  STEP(6,7,8,1,1,0,0)   STEP(7,8,9,1,1,1,0)                                 \
  STEP(8,9,10,1,1,2,0)  STEP(9,10,11,1,1,3,0)                               \
  STEP(10,11,12,0,0,0,0) STEP(11,12,13,0,0,0,0)                             \
  STEP(12,13,14,0,0,0,0) STEP(13,14,15,0,0,0,0) }

#define S4_V14 { STAGE_BEGIN                                                \
  STEP(0,1,2,0,0,0,0)   STEP(1,2,3,0,0,0,0)   STEP(2,3,4,0,0,0,0)           \
  STEP(3,4,5,1,0,0,0)   STEP(4,5,6,1,0,0,0)                                 \
  STEP(5,6,7,1,1,0,0)   STEP(6,7,8,1,1,1,0)                                 \
  STEP(7,8,9,1,1,2,0)   STEP(8,9,10,1,1,3,0)                                \
  STEP(9,10,11,0,0,0,0) STEP(10,11,12,0,0,0,0) STEP(11,12,13,0,0,0,0) }

#define S4_V12 { STAGE_BEGIN                                                \
  STEP(0,1,2,0,0,0,0)   STEP(1,2,3,0,0,0,0)                                 \
  STEP(2,3,4,1,0,0,0)   STEP(3,4,5,1,0,0,0)                                 \
  STEP(4,5,6,1,1,0,0)   STEP(5,6,7,1,1,1,0)                                 \
  STEP(6,7,8,1,1,2,0)   STEP(7,8,9,1,1,3,0)                                 \
  STEP(8,9,10,0,0,0,0)  STEP(9,10,11,0,0,0,0) }

#define S4_V10 { STAGE_BEGIN                                                \
  STEP(0,1,2,0,0,0,0)                                                       \
  STEP(1,2,3,1,0,0,0)   STEP(2,3,4,1,0,0,0)                                 \
  STEP(3,4,5,1,1,0,0)   STEP(4,5,6,1,1,1,0)                                 \
  STEP(5,6,7,1,1,2,0)   STEP(6,7,8,1,1,3,0)                                 \
  STEP(7,8,9,0,0,0,0) }

#define S4_V8 { STAGE_BEGIN                                                 \
  STEP(0,1,2,1,0,0,0)   STEP(1,2,3,1,0,0,0)                                 \
  STEP(2,3,4,1,1,0,0)   STEP(3,4,5,1,1,1,0)                                 \
  STEP(4,5,6,1,1,2,0)   STEP(5,6,7,1,1,3,0) }

#define DECLF(i) uint32_t F##i##a, F##i##b;

#define COMMON_SETUP                                                        \
  const int l = threadIdx.x & 63;                                           \
  const int wid = threadIdx.x >> 6;                                         \
  const int w = blockIdx.x;                                                 \
  const int y0 = (blockIdx.y * 4 + wid) * RV;                               \
  const size_t base = (size_t)blockIdx.z * (size_t)(W * H);                 \
  const int rx = 208 * w - 8 + 4 * l;                                       \
  const int cq = min(max(rx, 0), W - 4);                                    \
  const bool mL = (rx == 0);                                                \
  const bool mR = (rx == W - 4);                                            \
  const bool top = (y0 == 0);                                               \
  const bool bot = (y0 + RV == H);                                          \
  const int wend = min(208 * (w + 1), W);                                   \
  const bool wr = (rx >= 208 * w) && (rx < wend);                           \
  const uint32_t ONE2 = 0x3C003C00u;

// Launch 1: stages 1..6 (skel init + iters 1..5); reads img f32, writes
// E6 (f16 packed) + skel. HALO=7, R=18.
__global__ __launch_bounds__(256) void skel6(const float* __restrict__ in,
                                             uint16_t* __restrict__ e16,
                                             float* __restrict__ skel) {
  COMMON_SETUP
  DECLF(0) DECLF(1) DECLF(2) DECLF(3) DECLF(4) DECLF(5) DECLF(6) DECLF(7)
  DECLF(8) DECLF(9) DECLF(10) DECLF(11) DECLF(12) DECLF(13) DECLF(14)
  DECLF(15) DECLF(16) DECLF(17)
  uint32_t Q0a, Q0b, Q1a, Q1b, Q2a, Q2b, Q3a, Q3b;

#define LOADROW1(i) {                                                       \
    const int gy = min(max(y0 - 7 + i, 0), H - 1);                          \
    const float4 v = *(const float4*)(in + base + (size_t)gy * W + cq);     \
    F##i##a = PK(v.x, v.y); F##i##b = PK(v.z, v.w); }
  LOADROW1(0) LOADROW1(1) LOADROW1(2) LOADROW1(3) LOADROW1(4) LOADROW1(5)
  LOADROW1(6) LOADROW1(7) LOADROW1(8) LOADROW1(9) LOADROW1(10) LOADROW1(11)
  LOADROW1(12) LOADROW1(13) LOADROW1(14) LOADROW1(15) LOADROW1(16)
  LOADROW1(17)
#undef LOADROW1

  S4_V18(1) S4_V16 S4_V14 S4_V12 S4_V10 S4_V8

  if (wr) {
#define STOREQ(k) {                                                         \
      float4 s;                                                             \
      s.x = 1.0f - CVTLO(Q##k##a); s.y = 1.0f - CVTHI(Q##k##a);             \
      s.z = 1.0f - CVTLO(Q##k##b); s.w = 1.0f - CVTHI(Q##k##b);             \
      *(float4*)(skel + base + (size_t)(y0 + k) * W + rx) = s; }
    STOREQ(0) STOREQ(1) STOREQ(2) STOREQ(3)
#undef STOREQ
    // E6 rows y0+k live in F(1+k) after 6 window shifts.
#define STOREE(k, j) {                                                      \
      *(uint2*)(e16 + base + (size_t)(y0 + k) * W + rx) =                   \
          make_uint2(F##j##a, F##j##b); }
    STOREE(0, 1) STOREE(1, 2) STOREE(2, 3) STOREE(3, 4)
#undef STOREE
  }
}

// Launch 2: stages 7..11 (iters 6..10); reads E6 (f16) + skel, writes skel.
// HALO=6, R=16.
__global__ __launch_bounds__(256) void skel5(const uint16_t* __restrict__ e16,
                                             float* __restrict__ skel) {
  COMMON_SETUP
  DECLF(0) DECLF(1) DECLF(2) DECLF(3) DECLF(4) DECLF(5) DECLF(6) DECLF(7)
  DECLF(8) DECLF(9) DECLF(10) DECLF(11) DECLF(12) DECLF(13) DECLF(14)
  DECLF(15)
  uint32_t Q0a, Q0b, Q1a, Q1b, Q2a, Q2b, Q3a, Q3b;

#define LOADROW2(i) {                                                       \
    const int gy = min(max(y0 - 6 + i, 0), H - 1);                          \
    const uint2 v = *(const uint2*)(e16 + base + (size_t)gy * W + cq);      \
    F##i##a = v.x; F##i##b = v.y; }
  LOADROW2(0) LOADROW2(1) LOADROW2(2) LOADROW2(3) LOADROW2(4) LOADROW2(5)
  LOADROW2(6) LOADROW2(7) LOADROW2(8) LOADROW2(9) LOADROW2(10) LOADROW2(11)
  LOADROW2(12) LOADROW2(13) LOADROW2(14) LOADROW2(15)
#undef LOADROW2

#define LOADQ(k) {                                                          \
    const float4 s = *(const float4*)(skel + base + (size_t)(y0 + k) * W + cq); \
    Q##k##a = PK(1.0f - s.x, 1.0f - s.y);                                   \
    Q##k##b = PK(1.0f - s.z, 1.0f - s.w); }
  LOADQ(0) LOADQ(1) LOADQ(2) LOADQ(3)
#undef LOADQ

  S4_V16 S4_V14 S4_V12 S4_V10 S4_V8

  if (wr) {
#define STOREQ(k) {                                                         \
      float4 s;                                                             \
      s.x = 1.0f - CVTLO(Q##k##a); s.y = 1.0f - CVTHI(Q##k##a);             \
      s.z = 1.0f - CVTLO(Q##k##b); s.w = 1.0f - CVTHI(Q##k##b);             \
      *(float4*)(skel + base + (size_t)(y0 + k) * W + rx) = s; }
    STOREQ(0) STOREQ(1) STOREQ(2) STOREQ(3)
#undef STOREQ
  }
}

extern "C" void kernel_launch(void* const* d_in, const int* in_sizes, int n_in,
                              void* d_out, int out_size, void* d_ws,
                              size_t ws_size, hipStream_t stream) {
  const float* img = (const float*)d_in[0];
  float* skel = (float*)d_out;
  uint16_t* E = (uint16_t*)d_ws;  // 32 MiB f16 E6 between launches

  dim3 grid(5, H / (4 * RV), NBATCH);  // 5 x 64 x 16 blocks, 256 thr
  skel6<<<grid, 256, 0, stream>>>(img, E, skel);
  skel5<<<grid, 256, 0, stream>>>(E, skel);
}

// Round 12
// 108.412 us; speedup vs baseline: 5.7237x; 1.2706x over previous
//
#include <hip/hip_runtime.h>
#include <hip/hip_fp16.h>

// SoftMorphology soft-skeleton: columns-in-registers shuffle stencil, f16.
// Round-12 = round-10 geometry (RV=8, verified) x round-11 packed-f16 Q
// update (verified). Round-11 counters: VALUBusy 79% -> VALU-issue-bound;
// RV=4's halo redundancy (16.5 steps/output-row vs 11.25 at RV=8) is the
// remaining waste. VGPR=60 leaves room: RV=8 F-state 44 regs + Q 16 +
// temps ~= 100-125 < 128 => keeps 4 waves/SIMD.
//   - erode/dilate are min/max (selection) => f16-exact; only input
//     quantization (2^-11) + 10 f16 RN muls enter the error (<~1e-2).
//   - skel as q = 1-s, q *= 1 - relu(pm - dd) packed f16 (exact relu
//     identity for inputs in [0,1]).
// Two launches: skel6 = init + iters 1..5 (writes E6 f16 + skel),
// skel5 = iters 6..10. R = RV + 2*(S+1) = 22 / 20 packed rows.
// Per wave: 256 cols (4/lane as 2 half2), R rows in named scalars (NO
// arrays -- rounds 4-8 lesson: any array goes to scratch). Horizontal =
// 2 shuffles/row; 5 column windows (write 208x4+192), halo 8 >= S+1=7.
// Borders: clamped loads = replicate guards absorbed by erode (verified
// r5-r11); dilate exact extension via mL/mR overrides + top/bot h swaps.

#define W 1024
#define H 1024
#define NBATCH 16
#define RV 8

__device__ __forceinline__ uint32_t HMIN2(uint32_t a, uint32_t b) {
  uint32_t d;
  asm("v_pk_min_f16 %0, %1, %2" : "=v"(d) : "v"(a), "v"(b));
  return d;
}
__device__ __forceinline__ uint32_t HMAX2(uint32_t a, uint32_t b) {
  uint32_t d;
  asm("v_pk_max_f16 %0, %1, %2" : "=v"(d) : "v"(a), "v"(b));
  return d;
}
__device__ __forceinline__ uint32_t PKSUB(uint32_t a, uint32_t b) {
  uint32_t d;  // a - b (packed f16)
  asm("v_pk_add_f16 %0, %1, %2 neg_lo:[0,1] neg_hi:[0,1]"
      : "=v"(d) : "v"(a), "v"(b));
  return d;
}
__device__ __forceinline__ uint32_t PKMUL(uint32_t a, uint32_t b) {
  uint32_t d;
  asm("v_pk_mul_f16 %0, %1, %2" : "=v"(d) : "v"(a), "v"(b));
  return d;
}
__device__ __forceinline__ uint32_t PKRELU(uint32_t a) {
  uint32_t d;  // max(a, 0) packed
  asm("v_pk_max_f16 %0, %1, 0" : "=v"(d) : "v"(a));
  return d;
}
__device__ __forceinline__ uint32_t PK(float x, float y) {
  __half2 h = __floats2half2_rn(x, y);
  return *(uint32_t*)&h;
}
__device__ __forceinline__ float CVTLO(uint32_t u) {
  uint16_t t = (uint16_t)(u & 0xffffu);
  __half h = *(__half*)&t;
  return __half2float(h);
}
__device__ __forceinline__ float CVTHI(uint32_t u) {
  uint16_t t = (uint16_t)(u >> 16);
  __half h = *(__half*)&t;
  return __half2float(h);
}

// One pipeline step: erode (row P <- min-cross of PM,C,N), rolling h-max,
// packed-f16 skel-q update for row K. All indices literal tokens.
#define STEP(P, C, N, DOH, DOU, K, INIT) {                                  \
  const uint32_t ca = F##C##a, cb = F##C##b;                                \
  const uint32_t na = F##N##a, nb = F##N##b;                                \
  const uint32_t vma = HMIN2(HMIN2(PMa, ca), na);                           \
  const uint32_t vmb = HMIN2(HMIN2(PMb, cb), nb);                           \
  const uint32_t t = (uint32_t)__shfl_up((int)cb, 1, 64);                   \
  const uint32_t r = (uint32_t)__shfl_down((int)ca, 1, 64);                 \
  const uint32_t m1 = mL ? (ca & 0xffffu) : (t >> 16);                      \
  const uint32_t r4 = mR ? (cb >> 16) : (r & 0xffffu);                      \
  const uint32_t sla = (ca >> 16) | (cb << 16);                             \
  const uint32_t slb = (cb >> 16) | (r4 << 16);                             \
  const uint32_t sra = m1 | (ca << 16);                                     \
  const uint32_t ea = HMIN2(vma, HMIN2(sra, sla));                          \
  const uint32_t eb = HMIN2(vmb, HMIN2(sla, slb));                          \
  if (DOH) {                                                                \
    const uint32_t te = (uint32_t)__shfl_up((int)eb, 1, 64);                \
    const uint32_t re = (uint32_t)__shfl_down((int)ea, 1, 64);              \
    const uint32_t em1 = mL ? (ea & 0xffffu) : (te >> 16);                  \
    const uint32_t er4 = mR ? (eb >> 16) : (re & 0xffffu);                  \
    const uint32_t esla = (ea >> 16) | (eb << 16);                          \
    const uint32_t eslb = (eb >> 16) | (er4 << 16);                         \
    const uint32_t esra = em1 | (ea << 16);                                 \
    const uint32_t hca = HMAX2(ea, HMAX2(esra, esla));                      \
    const uint32_t hcb = HMAX2(eb, HMAX2(esla, eslb));                      \
    if (DOU) {                                                              \
      uint32_t haa = h2a, hab = h2b, hba = hca, hbb = hcb;                  \
      if (K == 0 && top) { haa = h1a; hab = h1b; }                          \
      if (K == RV - 1 && bot) { hba = h1a; hbb = h1b; }                     \
      const uint32_t dda = HMAX2(HMAX2(haa, h1a), hba);                     \
      const uint32_t ddb = HMAX2(HMAX2(hab, h1b), hbb);                     \
      const uint32_t fa = PKSUB(ONE2, PKRELU(PKSUB(PMa, dda)));             \
      const uint32_t fb = PKSUB(ONE2, PKRELU(PKSUB(PMb, ddb)));             \
      if (INIT) { Q##K##a = fa; Q##K##b = fb; }                             \
      else { Q##K##a = PKMUL(Q##K##a, fa); Q##K##b = PKMUL(Q##K##b, fb); }  \
    }                                                                       \
    h2a = h1a; h2b = h1b; h1a = hca; h1b = hcb;                             \
  }                                                                         \
  F##P##a = ea; F##P##b = eb;                                               \
  PMa = ca; PMb = cb;                                                       \
}

#define STAGE_BEGIN uint32_t PMa = F0a, PMb = F0b,                          \
    h1a = 0, h1b = 0, h2a = 0, h2b = 0;

// RV=8 stage bodies by valid-row count V; HT = (V-RV-2)/2.
// DOH window i in [HT, HT+RV+1], DOU i in [HT+2, HT+RV+1], K = i-2-HT.
#define S_V22(INIT) { STAGE_BEGIN                                           \
  STEP(0,1,2,0,0,0,INIT)  STEP(1,2,3,0,0,0,INIT)  STEP(2,3,4,0,0,0,INIT)    \
  STEP(3,4,5,0,0,0,INIT)  STEP(4,5,6,0,0,0,INIT)                            \
  STEP(5,6,7,1,0,0,INIT)  STEP(6,7,8,1,0,0,INIT)                            \
  STEP(7,8,9,1,1,0,INIT)  STEP(8,9,10,1,1,1,INIT) STEP(9,10,11,1,1,2,INIT)  \
  STEP(10,11,12,1,1,3,INIT) STEP(11,12,13,1,1,4,INIT)                       \
  STEP(12,13,14,1,1,5,INIT) STEP(13,14,15,1,1,6,INIT)                       \
  STEP(14,15,16,1,1,7,INIT)                                                 \
  STEP(15,16,17,0,0,0,INIT) STEP(16,17,18,0,0,0,INIT)                       \
  STEP(17,18,19,0,0,0,INIT) STEP(18,19,20,0,0,0,INIT)                       \
  STEP(19,20,21,0,0,0,INIT) }

#define S_V20 { STAGE_BEGIN                                                 \
  STEP(0,1,2,0,0,0,0)   STEP(1,2,3,0,0,0,0)   STEP(2,3,4,0,0,0,0)           \
  STEP(3,4,5,0,0,0,0)                                                       \
  STEP(4,5,6,1,0,0,0)   STEP(5,6,7,1,0,0,0)                                 \
  STEP(6,7,8,1,1,0,0)   STEP(7,8,9,1,1,1,0)   STEP(8,9,10,1,1,2,0)          \
  STEP(9,10,11,1,1,3,0) STEP(10,11,12,1,1,4,0) STEP(11,12,13,1,1,5,0)       \
  STEP(12,13,14,1,1,6,0) STEP(13,14,15,1,1,7,0)                             \
  STEP(14,15,16,0,0,0,0) STEP(15,16,17,0,0,0,0) STEP(16,17,18,0,0,0,0)      \
  STEP(17,18,19,0,0,0,0) }

#define S_V18 { STAGE_BEGIN                                                 \
  STEP(0,1,2,0,0,0,0)   STEP(1,2,3,0,0,0,0)   STEP(2,3,4,0,0,0,0)           \
  STEP(3,4,5,1,0,0,0)   STEP(4,5,6,1,0,0,0)                                 \
  STEP(5,6,7,1,1,0,0)   STEP(6,7,8,1,1,1,0)   STEP(7,8,9,1,1,2,0)           \
  STEP(8,9,10,1,1,3,0)  STEP(9,10,11,1,1,4,0) STEP(10,11,12,1,1,5,0)        \
  STEP(11,12,13,1,1,6,0) STEP(12,13,14,1,1,7,0)                             \
  STEP(13,14,15,0,0,0,0) STEP(14,15,16,0,0,0,0) STEP(15,16,17,0,0,0,0) }

#define S_V16 { STAGE_BEGIN                                                 \
  STEP(0,1,2,0,0,0,0)   STEP(1,2,3,0,0,0,0)                                 \
  STEP(2,3,4,1,0,0,0)   STEP(3,4,5,1,0,0,0)                                 \
  STEP(4,5,6,1,1,0,0)   STEP(5,6,7,1,1,1,0)   STEP(6,7,8,1,1,2,0)           \
  STEP(7,8,9,1,1,3,0)   STEP(8,9,10,1,1,4,0)  STEP(9,10,11,1,1,5,0)         \
  STEP(10,11,12,1,1,6,0) STEP(11,12,13,1,1,7,0)                             \
  STEP(12,13,14,0,0,0,0) STEP(13,14,15,0,0,0,0) }

#define S_V14 { STAGE_BEGIN                                                 \
  STEP(0,1,2,0,0,0,0)                                                       \
  STEP(1,2,3,1,0,0,0)   STEP(2,3,4,1,0,0,0)                                 \
  STEP(3,4,5,1,1,0,0)   STEP(4,5,6,1,1,1,0)   STEP(5,6,7,1,1,2,0)           \
  STEP(6,7,8,1,1,3,0)   STEP(7,8,9,1,1,4,0)   STEP(8,9,10,1,1,5,0)          \
  STEP(9,10,11,1,1,6,0) STEP(10,11,12,1,1,7,0)                              \
  STEP(11,12,13,0,0,0,0) }

#define S_V12 { STAGE_BEGIN                                                 \
  STEP(0,1,2,1,0,0,0)   STEP(1,2,3,1,0,0,0)                                 \
  STEP(2,3,4,1,1,0,0)   STEP(3,4,5,1,1,1,0)   STEP(4,5,6,1,1,2,0)           \
  STEP(5,6,7,1,1,3,0)   STEP(6,7,8,1,1,4,0)   STEP(7,8,9,1,1,5,0)           \
  STEP(8,9,10,1,1,6,0)  STEP(9,10,11,1,1,7,0) }

#define DECLF(i) uint32_t F##i##a, F##i##b;

#define COMMON_SETUP                                                        \
  const int l = threadIdx.x & 63;                                           \
  const int wid = threadIdx.x >> 6;                                         \
  const int w = blockIdx.x;                                                 \
  const int y0 = (blockIdx.y * 4 + wid) * RV;                               \
  const size_t base = (size_t)blockIdx.z * (size_t)(W * H);                 \
  const int rx = 208 * w - 8 + 4 * l;                                       \
  const int cq = min(max(rx, 0), W - 4);                                    \
  const bool mL = (rx == 0);                                                \
  const bool mR = (rx == W - 4);                                            \
  const bool top = (y0 == 0);                                               \
  const bool bot = (y0 + RV == H);                                          \
  const int wend = min(208 * (w + 1), W);                                   \
  const bool wr = (rx >= 208 * w) && (rx < wend);                           \
  const uint32_t ONE2 = 0x3C003C00u;

// Launch 1: stages 1..6 (skel init + iters 1..5); reads img f32, writes
// E6 (f16 packed) + skel. HALO=7, R=22.
__global__ __launch_bounds__(256) void skel6(const float* __restrict__ in,
                                             uint16_t* __restrict__ e16,
                                             float* __restrict__ skel) {
  COMMON_SETUP
  DECLF(0) DECLF(1) DECLF(2) DECLF(3) DECLF(4) DECLF(5) DECLF(6) DECLF(7)
  DECLF(8) DECLF(9) DECLF(10) DECLF(11) DECLF(12) DECLF(13) DECLF(14)
  DECLF(15) DECLF(16) DECLF(17) DECLF(18) DECLF(19) DECLF(20) DECLF(21)
  uint32_t Q0a, Q0b, Q1a, Q1b, Q2a, Q2b, Q3a, Q3b;
  uint32_t Q4a, Q4b, Q5a, Q5b, Q6a, Q6b, Q7a, Q7b;

#define LOADROW1(i) {                                                       \
    const int gy = min(max(y0 - 7 + i, 0), H - 1);                          \
    const float4 v = *(const float4*)(in + base + (size_t)gy * W + cq);     \
    F##i##a = PK(v.x, v.y); F##i##b = PK(v.z, v.w); }
  LOADROW1(0) LOADROW1(1) LOADROW1(2) LOADROW1(3) LOADROW1(4) LOADROW1(5)
  LOADROW1(6) LOADROW1(7) LOADROW1(8) LOADROW1(9) LOADROW1(10) LOADROW1(11)
  LOADROW1(12) LOADROW1(13) LOADROW1(14) LOADROW1(15) LOADROW1(16)
  LOADROW1(17) LOADROW1(18) LOADROW1(19) LOADROW1(20) LOADROW1(21)
#undef LOADROW1

  S_V22(1) S_V20 S_V18 S_V16 S_V14 S_V12

  if (wr) {
#define STOREQ(k) {                                                         \
      float4 s;                                                             \
      s.x = 1.0f - CVTLO(Q##k##a); s.y = 1.0f - CVTHI(Q##k##a);             \
      s.z = 1.0f - CVTLO(Q##k##b); s.w = 1.0f - CVTHI(Q##k##b);             \
      *(float4*)(skel + base + (size_t)(y0 + k) * W + rx) = s; }
    STOREQ(0) STOREQ(1) STOREQ(2) STOREQ(3)
    STOREQ(4) STOREQ(5) STOREQ(6) STOREQ(7)
#undef STOREQ
    // E6 rows y0+k live in F(1+k) after 6 window shifts.
#define STOREE(k, j) {                                                      \
      *(uint2*)(e16 + base + (size_t)(y0 + k) * W + rx) =                   \
          make_uint2(F##j##a, F##j##b); }
    STOREE(0, 1) STOREE(1, 2) STOREE(2, 3) STOREE(3, 4)
    STOREE(4, 5) STOREE(5, 6) STOREE(6, 7) STOREE(7, 8)
#undef STOREE
  }
}

// Launch 2: stages 7..11 (iters 6..10); reads E6 (f16) + skel, writes skel.
// HALO=6, R=20.
__global__ __launch_bounds__(256) void skel5(const uint16_t* __restrict__ e16,
                                             float* __restrict__ skel) {
  COMMON_SETUP
  DECLF(0) DECLF(1) DECLF(2) DECLF(3) DECLF(4) DECLF(5) DECLF(6) DECLF(7)
  DECLF(8) DECLF(9) DECLF(10) DECLF(11) DECLF(12) DECLF(13) DECLF(14)
  DECLF(15) DECLF(16) DECLF(17) DECLF(18) DECLF(19)
  uint32_t Q0a, Q0b, Q1a, Q1b, Q2a, Q2b, Q3a, Q3b;
  uint32_t Q4a, Q4b, Q5a, Q5b, Q6a, Q6b, Q7a, Q7b;

#define LOADROW2(i) {                                                       \
    const int gy = min(max(y0 - 6 + i, 0), H - 1);                          \
    const uint2 v = *(const uint2*)(e16 + base + (size_t)gy * W + cq);      \
    F##i##a = v.x; F##i##b = v.y; }
  LOADROW2(0) LOADROW2(1) LOADROW2(2) LOADROW2(3) LOADROW2(4) LOADROW2(5)
  LOADROW2(6) LOADROW2(7) LOADROW2(8) LOADROW2(9) LOADROW2(10) LOADROW2(11)
  LOADROW2(12) LOADROW2(13) LOADROW2(14) LOADROW2(15) LOADROW2(16)
  LOADROW2(17) LOADROW2(18) LOADROW2(19)
#undef LOADROW2

#define LOADQ(k) {                                                          \
    const float4 s = *(const float4*)(skel + base + (size_t)(y0 + k) * W + cq); \
    Q##k##a = PK(1.0f - s.x, 1.0f - s.y);                                   \
    Q##k##b = PK(1.0f - s.z, 1.0f - s.w); }
  LOADQ(0) LOADQ(1) LOADQ(2) LOADQ(3) LOADQ(4) LOADQ(5) LOADQ(6) LOADQ(7)
#undef LOADQ

  S_V20 S_V18 S_V16 S_V14 S_V12

  if (wr) {
#define STOREQ(k) {                                                         \
      float4 s;                                                             \
      s.x = 1.0f - CVTLO(Q##k##a); s.y = 1.0f - CVTHI(Q##k##a);             \
      s.z = 1.0f - CVTLO(Q##k##b); s.w = 1.0f - CVTHI(Q##k##b);             \
      *(float4*)(skel + base + (size_t)(y0 + k) * W + rx) = s; }
    STOREQ(0) STOREQ(1) STOREQ(2) STOREQ(3)
    STOREQ(4) STOREQ(5) STOREQ(6) STOREQ(7)
#undef STOREQ
  }
}

extern "C" void kernel_launch(void* const* d_in, const int* in_sizes, int n_in,
                              void* d_out, int out_size, void* d_ws,
                              size_t ws_size, hipStream_t stream) {
  const float* img = (const float*)d_in[0];
  float* skel = (float*)d_out;
  uint16_t* E = (uint16_t*)d_ws;  // 32 MiB f16 E6 between launches

  dim3 grid(5, H / (4 * RV), NBATCH);  // 5 x 32 x 16 blocks, 256 thr
  skel6<<<grid, 256, 0, stream>>>(img, E, skel);
  skel5<<<grid, 256, 0, stream>>>(E, skel);
}

// Round 13
// 102.541 us; speedup vs baseline: 6.0513x; 1.0572x over previous
//
#include <hip/hip_runtime.h>
#include <hip/hip_fp16.h>

// SoftMorphology soft-skeleton: columns-in-registers stencil, f16, DPP.
// Round-13 = round-12 (RV=8, packed-f16 state, zero arrays) plus:
//  * DPP lane shifts instead of __shfl: __shfl_up/down(x,1,64) compiled to
//    ds_bpermute (LDS pipe, ~50-120cy latency on the dependent chain, 4
//    shuffles/step). v_mov_b32_dpp wave_shr:1 / wave_shl:1 is 1 VALU op,
//    no lgkm wait. Invalid-lane result = 0 (bound_ctrl): only affects
//    region-edge halo lanes, absorbed by the contamination margin
//    (<=1 col/stage inward, halo 8 > 7 needed); image-edge cols still get
//    exact extension via mL/mR overrides.
//  * skel handoff between launches as packed f16 q (32 MB) instead of f32
//    s (64 MB): -64 MB HBM round-trip + fewer CVTs; adds one f16 RN
//    quantization of q (<=2^-11). Final f32 skel written by skel5 only.
// Verified-invariant algorithm (r5-r12): erode/dilate are min/max ==>
// f16-exact; q = 1-s, q *= 1 - relu(pm - dd) (relu identity on [0,1]).
// skel6 = init + iters 1..5 (writes E6 f16 + q16), skel5 = iters 6..10
// (reads E6+q16, writes skel f32). R = RV+2*(S+1) = 22/20 packed rows.
// Per wave: 256 cols (4/lane as 2 half2), rows in named scalars (NO
// arrays -- any array goes to scratch, r4-r8 lesson). 5 column windows
// (write 208x4+192), halo 8 >= 7. Borders: clamped loads = replicate
// guards absorbed by erode; dilate exact via mL/mR + top/bot h swaps.

#define W 1024
#define H 1024
#define NBATCH 16
#define RV 8

__device__ __forceinline__ uint32_t HMIN2(uint32_t a, uint32_t b) {
  uint32_t d;
  asm("v_pk_min_f16 %0, %1, %2" : "=v"(d) : "v"(a), "v"(b));
  return d;
}
__device__ __forceinline__ uint32_t HMAX2(uint32_t a, uint32_t b) {
  uint32_t d;
  asm("v_pk_max_f16 %0, %1, %2" : "=v"(d) : "v"(a), "v"(b));
  return d;
}
__device__ __forceinline__ uint32_t PKSUB(uint32_t a, uint32_t b) {
  uint32_t d;  // a - b (packed f16)
  asm("v_pk_add_f16 %0, %1, %2 neg_lo:[0,1] neg_hi:[0,1]"
      : "=v"(d) : "v"(a), "v"(b));
  return d;
}
__device__ __forceinline__ uint32_t PKMUL(uint32_t a, uint32_t b) {
  uint32_t d;
  asm("v_pk_mul_f16 %0, %1, %2" : "=v"(d) : "v"(a), "v"(b));
  return d;
}
__device__ __forceinline__ uint32_t PKRELU(uint32_t a) {
  uint32_t d;  // max(a, 0) packed
  asm("v_pk_max_f16 %0, %1, 0" : "=v"(d) : "v"(a));
  return d;
}
__device__ __forceinline__ uint32_t PK(float x, float y) {
  __half2 h = __floats2half2_rn(x, y);
  return *(uint32_t*)&h;
}
__device__ __forceinline__ float CVTLO(uint32_t u) {
  uint16_t t = (uint16_t)(u & 0xffffu);
  __half h = *(__half*)&t;
  return __half2float(h);
}
__device__ __forceinline__ float CVTHI(uint32_t u) {
  uint16_t t = (uint16_t)(u >> 16);
  __half h = *(__half*)&t;
  return __half2float(h);
}
// DPP wave shifts: lane i <- lane i-1 (SHUP) / lane i+1 (SHDN); invalid
// lane gets 0 (bound_ctrl) -- lands in halo contamination zone only.
__device__ __forceinline__ uint32_t SHUP(uint32_t x) {  // wave_shr:1
  return (uint32_t)__builtin_amdgcn_update_dpp(0, (int)x, 0x138, 0xf, 0xf,
                                               true);
}
__device__ __forceinline__ uint32_t SHDN(uint32_t x) {  // wave_shl:1
  return (uint32_t)__builtin_amdgcn_update_dpp(0, (int)x, 0x130, 0xf, 0xf,
                                               true);
}

// One pipeline step: erode (row P <- min-cross of PM,C,N), rolling h-max,
// packed-f16 skel-q update for row K. All indices literal tokens.
#define STEP(P, C, N, DOH, DOU, K, INIT) {                                  \
  const uint32_t ca = F##C##a, cb = F##C##b;                                \
  const uint32_t na = F##N##a, nb = F##N##b;                                \
  const uint32_t vma = HMIN2(HMIN2(PMa, ca), na);                           \
  const uint32_t vmb = HMIN2(HMIN2(PMb, cb), nb);                           \
  const uint32_t t = SHUP(cb);                                              \
  const uint32_t r = SHDN(ca);                                              \
  const uint32_t m1 = mL ? (ca & 0xffffu) : (t >> 16);                      \
  const uint32_t r4 = mR ? (cb >> 16) : (r & 0xffffu);                      \
  const uint32_t sla = (ca >> 16) | (cb << 16);                             \
  const uint32_t slb = (cb >> 16) | (r4 << 16);                             \
  const uint32_t sra = m1 | (ca << 16);                                     \
  const uint32_t ea = HMIN2(vma, HMIN2(sra, sla));                          \
  const uint32_t eb = HMIN2(vmb, HMIN2(sla, slb));                          \
  if (DOH) {                                                                \
    const uint32_t te = SHUP(eb);                                           \
    const uint32_t re = SHDN(ea);                                           \
    const uint32_t em1 = mL ? (ea & 0xffffu) : (te >> 16);                  \
    const uint32_t er4 = mR ? (eb >> 16) : (re & 0xffffu);                  \
    const uint32_t esla = (ea >> 16) | (eb << 16);                          \
    const uint32_t eslb = (eb >> 16) | (er4 << 16);                         \
    const uint32_t esra = em1 | (ea << 16);                                 \
    const uint32_t hca = HMAX2(ea, HMAX2(esra, esla));                      \
    const uint32_t hcb = HMAX2(eb, HMAX2(esla, eslb));                      \
    if (DOU) {                                                              \
      uint32_t haa = h2a, hab = h2b, hba = hca, hbb = hcb;                  \
      if (K == 0 && top) { haa = h1a; hab = h1b; }                          \
      if (K == RV - 1 && bot) { hba = h1a; hbb = h1b; }                     \
      const uint32_t dda = HMAX2(HMAX2(haa, h1a), hba);                     \
      const uint32_t ddb = HMAX2(HMAX2(hab, h1b), hbb);                     \
      const uint32_t fa = PKSUB(ONE2, PKRELU(PKSUB(PMa, dda)));             \
      const uint32_t fb = PKSUB(ONE2, PKRELU(PKSUB(PMb, ddb)));             \
      if (INIT) { Q##K##a = fa; Q##K##b = fb; }                             \
      else { Q##K##a = PKMUL(Q##K##a, fa); Q##K##b = PKMUL(Q##K##b, fb); }  \
    }                                                                       \
    h2a = h1a; h2b = h1b; h1a = hca; h1b = hcb;                             \
  }                                                                         \
  F##P##a = ea; F##P##b = eb;                                               \
  PMa = ca; PMb = cb;                                                       \
}

#define STAGE_BEGIN uint32_t PMa = F0a, PMb = F0b,                          \
    h1a = 0, h1b = 0, h2a = 0, h2b = 0;

// RV=8 stage bodies by valid-row count V; HT = (V-RV-2)/2.
// DOH window i in [HT, HT+RV+1], DOU i in [HT+2, HT+RV+1], K = i-2-HT.
#define S_V22(INIT) { STAGE_BEGIN                                           \
  STEP(0,1,2,0,0,0,INIT)  STEP(1,2,3,0,0,0,INIT)  STEP(2,3,4,0,0,0,INIT)    \
  STEP(3,4,5,0,0,0,INIT)  STEP(4,5,6,0,0,0,INIT)                            \
  STEP(5,6,7,1,0,0,INIT)  STEP(6,7,8,1,0,0,INIT)                            \
  STEP(7,8,9,1,1,0,INIT)  STEP(8,9,10,1,1,1,INIT) STEP(9,10,11,1,1,2,INIT)  \
  STEP(10,11,12,1,1,3,INIT) STEP(11,12,13,1,1,4,INIT)                       \
  STEP(12,13,14,1,1,5,INIT) STEP(13,14,15,1,1,6,INIT)                       \
  STEP(14,15,16,1,1,7,INIT)                                                 \
  STEP(15,16,17,0,0,0,INIT) STEP(16,17,18,0,0,0,INIT)                       \
  STEP(17,18,19,0,0,0,INIT) STEP(18,19,20,0,0,0,INIT)                       \
  STEP(19,20,21,0,0,0,INIT) }

#define S_V20 { STAGE_BEGIN                                                 \
  STEP(0,1,2,0,0,0,0)   STEP(1,2,3,0,0,0,0)   STEP(2,3,4,0,0,0,0)           \
  STEP(3,4,5,0,0,0,0)                                                       \
  STEP(4,5,6,1,0,0,0)   STEP(5,6,7,1,0,0,0)                                 \
  STEP(6,7,8,1,1,0,0)   STEP(7,8,9,1,1,1,0)   STEP(8,9,10,1,1,2,0)          \
  STEP(9,10,11,1,1,3,0) STEP(10,11,12,1,1,4,0) STEP(11,12,13,1,1,5,0)       \
  STEP(12,13,14,1,1,6,0) STEP(13,14,15,1,1,7,0)                             \
  STEP(14,15,16,0,0,0,0) STEP(15,16,17,0,0,0,0) STEP(16,17,18,0,0,0,0)      \
  STEP(17,18,19,0,0,0,0) }

#define S_V18 { STAGE_BEGIN                                                 \
  STEP(0,1,2,0,0,0,0)   STEP(1,2,3,0,0,0,0)   STEP(2,3,4,0,0,0,0)           \
  STEP(3,4,5,1,0,0,0)   STEP(4,5,6,1,0,0,0)                                 \
  STEP(5,6,7,1,1,0,0)   STEP(6,7,8,1,1,1,0)   STEP(7,8,9,1,1,2,0)           \
  STEP(8,9,10,1,1,3,0)  STEP(9,10,11,1,1,4,0) STEP(10,11,12,1,1,5,0)        \
  STEP(11,12,13,1,1,6,0) STEP(12,13,14,1,1,7,0)                             \
  STEP(13,14,15,0,0,0,0) STEP(14,15,16,0,0,0,0) STEP(15,16,17,0,0,0,0) }

#define S_V16 { STAGE_BEGIN                                                 \
  STEP(0,1,2,0,0,0,0)   STEP(1,2,3,0,0,0,0)                                 \
  STEP(2,3,4,1,0,0,0)   STEP(3,4,5,1,0,0,0)                                 \
  STEP(4,5,6,1,1,0,0)   STEP(5,6,7,1,1,1,0)   STEP(6,7,8,1,1,2,0)           \
  STEP(7,8,9,1,1,3,0)   STEP(8,9,10,1,1,4,0)  STEP(9,10,11,1,1,5,0)         \
  STEP(10,11,12,1,1,6,0) STEP(11,12,13,1,1,7,0)                             \
  STEP(12,13,14,0,0,0,0) STEP(13,14,15,0,0,0,0) }

#define S_V14 { STAGE_BEGIN                                                 \
  STEP(0,1,2,0,0,0,0)                                                       \
  STEP(1,2,3,1,0,0,0)   STEP(2,3,4,1,0,0,0)                                 \
  STEP(3,4,5,1,1,0,0)   STEP(4,5,6,1,1,1,0)   STEP(5,6,7,1,1,2,0)           \
  STEP(6,7,8,1,1,3,0)   STEP(7,8,9,1,1,4,0)   STEP(8,9,10,1,1,5,0)          \
  STEP(9,10,11,1,1,6,0) STEP(10,11,12,1,1,7,0)                              \
  STEP(11,12,13,0,0,0,0) }

#define S_V12 { STAGE_BEGIN                                                 \
  STEP(0,1,2,1,0,0,0)   STEP(1,2,3,1,0,0,0)                                 \
  STEP(2,3,4,1,1,0,0)   STEP(3,4,5,1,1,1,0)   STEP(4,5,6,1,1,2,0)           \
  STEP(5,6,7,1,1,3,0)   STEP(6,7,8,1,1,4,0)   STEP(7,8,9,1,1,5,0)           \
  STEP(8,9,10,1,1,6,0)  STEP(9,10,11,1,1,7,0) }

#define DECLF(i) uint32_t F##i##a, F##i##b;

#define COMMON_SETUP                                                        \
  const int l = threadIdx.x & 63;                                           \
  const int wid = threadIdx.x >> 6;                                         \
  const int w = blockIdx.x;                                                 \
  const int y0 = (blockIdx.y * 4 + wid) * RV;                               \
  const size_t base = (size_t)blockIdx.z * (size_t)(W * H);                 \
  const int rx = 208 * w - 8 + 4 * l;                                       \
  const int cq = min(max(rx, 0), W - 4);                                    \
  const bool mL = (rx == 0);                                                \
  const bool mR = (rx == W - 4);                                            \
  const bool top = (y0 == 0);                                               \
  const bool bot = (y0 + RV == H);                                          \
  const int wend = min(208 * (w + 1), W);                                   \
  const bool wr = (rx >= 208 * w) && (rx < wend);                           \
  const uint32_t ONE2 = 0x3C003C00u;

// Launch 1: stages 1..6 (skel init + iters 1..5); reads img f32, writes
// E6 (f16 packed) + q16 (f16 packed skel complement). HALO=7, R=22.
__global__ __launch_bounds__(256) void skel6(const float* __restrict__ in,
                                             uint16_t* __restrict__ e16,
                                             uint16_t* __restrict__ q16) {
  COMMON_SETUP
  DECLF(0) DECLF(1) DECLF(2) DECLF(3) DECLF(4) DECLF(5) DECLF(6) DECLF(7)
  DECLF(8) DECLF(9) DECLF(10) DECLF(11) DECLF(12) DECLF(13) DECLF(14)
  DECLF(15) DECLF(16) DECLF(17) DECLF(18) DECLF(19) DECLF(20) DECLF(21)
  uint32_t Q0a, Q0b, Q1a, Q1b, Q2a, Q2b, Q3a, Q3b;
  uint32_t Q4a, Q4b, Q5a, Q5b, Q6a, Q6b, Q7a, Q7b;

#define LOADROW1(i) {                                                       \
    const int gy = min(max(y0 - 7 + i, 0), H - 1);                          \
    const float4 v = *(const float4*)(in + base + (size_t)gy * W + cq);     \
    F##i##a = PK(v.x, v.y); F##i##b = PK(v.z, v.w); }
  LOADROW1(0) LOADROW1(1) LOADROW1(2) LOADROW1(3) LOADROW1(4) LOADROW1(5)
  LOADROW1(6) LOADROW1(7) LOADROW1(8) LOADROW1(9) LOADROW1(10) LOADROW1(11)
  LOADROW1(12) LOADROW1(13) LOADROW1(14) LOADROW1(15) LOADROW1(16)
  LOADROW1(17) LOADROW1(18) LOADROW1(19) LOADROW1(20) LOADROW1(21)
#undef LOADROW1

  S_V22(1) S_V20 S_V18 S_V16 S_V14 S_V12

  if (wr) {
#define STOREQ(k) {                                                         \
      *(uint2*)(q16 + base + (size_t)(y0 + k) * W + rx) =                   \
          make_uint2(Q##k##a, Q##k##b); }
    STOREQ(0) STOREQ(1) STOREQ(2) STOREQ(3)
    STOREQ(4) STOREQ(5) STOREQ(6) STOREQ(7)
#undef STOREQ
    // E6 rows y0+k live in F(1+k) after 6 window shifts.
#define STOREE(k, j) {                                                      \
      *(uint2*)(e16 + base + (size_t)(y0 + k) * W + rx) =                   \
          make_uint2(F##j##a, F##j##b); }
    STOREE(0, 1) STOREE(1, 2) STOREE(2, 3) STOREE(3, 4)
    STOREE(4, 5) STOREE(5, 6) STOREE(6, 7) STOREE(7, 8)
#undef STOREE
  }
}

// Launch 2: stages 7..11 (iters 6..10); reads E6 + q16, writes skel f32.
// HALO=6, R=20.
__global__ __launch_bounds__(256) void skel5(const uint16_t* __restrict__ e16,
                                             const uint16_t* __restrict__ q16,
                                             float* __restrict__ skel) {
  COMMON_SETUP
  DECLF(0) DECLF(1) DECLF(2) DECLF(3) DECLF(4) DECLF(5) DECLF(6) DECLF(7)
  DECLF(8) DECLF(9) DECLF(10) DECLF(11) DECLF(12) DECLF(13) DECLF(14)
  DECLF(15) DECLF(16) DECLF(17) DECLF(18) DECLF(19)
  uint32_t Q0a, Q0b, Q1a, Q1b, Q2a, Q2b, Q3a, Q3b;
  uint32_t Q4a, Q4b, Q5a, Q5b, Q6a, Q6b, Q7a, Q7b;

#define LOADROW2(i) {                                                       \
    const int gy = min(max(y0 - 6 + i, 0), H - 1);                          \
    const uint2 v = *(const uint2*)(e16 + base + (size_t)gy * W + cq);      \
    F##i##a = v.x; F##i##b = v.y; }
  LOADROW2(0) LOADROW2(1) LOADROW2(2) LOADROW2(3) LOADROW2(4) LOADROW2(5)
  LOADROW2(6) LOADROW2(7) LOADROW2(8) LOADROW2(9) LOADROW2(10) LOADROW2(11)
  LOADROW2(12) LOADROW2(13) LOADROW2(14) LOADROW2(15) LOADROW2(16)
  LOADROW2(17) LOADROW2(18) LOADROW2(19)
#undef LOADROW2

#define LOADQ(k) {                                                          \
    const uint2 v = *(const uint2*)(q16 + base + (size_t)(y0 + k) * W + cq); \
    Q##k##a = v.x; Q##k##b = v.y; }
  LOADQ(0) LOADQ(1) LOADQ(2) LOADQ(3) LOADQ(4) LOADQ(5) LOADQ(6) LOADQ(7)
#undef LOADQ

  S_V20 S_V18 S_V16 S_V14 S_V12

  if (wr) {
#define STOREQ(k) {                                                         \
      float4 s;                                                             \
      s.x = 1.0f - CVTLO(Q##k##a); s.y = 1.0f - CVTHI(Q##k##a);             \
      s.z = 1.0f - CVTLO(Q##k##b); s.w = 1.0f - CVTHI(Q##k##b);             \
      *(float4*)(skel + base + (size_t)(y0 + k) * W + rx) = s; }
    STOREQ(0) STOREQ(1) STOREQ(2) STOREQ(3)
    STOREQ(4) STOREQ(5) STOREQ(6) STOREQ(7)
#undef STOREQ
  }
}

extern "C" void kernel_launch(void* const* d_in, const int* in_sizes, int n_in,
                              void* d_out, int out_size, void* d_ws,
                              size_t ws_size, hipStream_t stream) {
  const float* img = (const float*)d_in[0];
  float* skel = (float*)d_out;
  const size_t NPIX = (size_t)NBATCH * W * H;
  uint16_t* E = (uint16_t*)d_ws;        // 32 MiB f16 E6
  uint16_t* Q = E + NPIX;               // 32 MiB f16 q (skel complement)

  dim3 grid(5, H / (4 * RV), NBATCH);  // 5 x 32 x 16 blocks, 256 thr
  skel6<<<grid, 256, 0, stream>>>(img, E, Q);
  skel5<<<grid, 256, 0, stream>>>(E, Q, skel);
}

// Round 14
// 101.137 us; speedup vs baseline: 6.1353x; 1.0139x over previous
//
#include <hip/hip_runtime.h>
#include <hip/hip_fp16.h>

// SoftMorphology soft-skeleton: columns-in-registers stencil, f16, DPP.
// Round-14 = round-13 structure (zero arrays, packed-f16 state, DPP lane
// shifts, f16 E6/q16 handoff) with RV 8 -> 16: pipeline steps per output
// row drop 22 -> 15.5 (-30% VALU work, the r13 bottleneck: VALUBusy 73%).
// F-state 60 regs + Q 32; r12/r13 showed the allocator is frugal (est.
// 100-125 -> actual 68-72), so projected ~95-125 VGPR keeps 4 waves/SIMD.
// 128-thread blocks (2 waves) for finer scheduling granularity.
//
// Verified-invariant algorithm (r5-r13): erode = min 5-pt cross, dilate =
// max 3x3 (both selection ops => f16-exact); q = 1-s, q *= 1-relu(pm-dd)
// (== s += relu(d - s*d) exactly, relu identity on [0,1]).
// skel6 = init + iters 1..5 (img f32 -> E6 f16 + q16 f16);
// skel5 = iters 6..10 (E6+q16 -> skel f32).
// R = RV + 2*(S+1) = 30 / 28 packed rows/lane; per-stage window shifts up
// one row; stage T has HT = HALO-T, DOH i in [HT, HT+RV+1], DOU i in
// [HT+2, HT+RV+1], K = i-2-HT (window algebra re-verified for R=30).
// Borders: clamped loads = replicate guards absorbed by erode; dilate gets
// exact extension via mL/mR lane overrides + top/bot h-row swaps. DPP
// invalid-lane zeros land only in the region-edge contamination margin
// (<=1 col/stage inward, halo 8 >= S+1=7).

#define W 1024
#define H 1024
#define NBATCH 16
#define RV 16

__device__ __forceinline__ uint32_t HMIN2(uint32_t a, uint32_t b) {
  uint32_t d;
  asm("v_pk_min_f16 %0, %1, %2" : "=v"(d) : "v"(a), "v"(b));
  return d;
}
__device__ __forceinline__ uint32_t HMAX2(uint32_t a, uint32_t b) {
  uint32_t d;
  asm("v_pk_max_f16 %0, %1, %2" : "=v"(d) : "v"(a), "v"(b));
  return d;
}
__device__ __forceinline__ uint32_t PKSUB(uint32_t a, uint32_t b) {
  uint32_t d;  // a - b (packed f16)
  asm("v_pk_add_f16 %0, %1, %2 neg_lo:[0,1] neg_hi:[0,1]"
      : "=v"(d) : "v"(a), "v"(b));
  return d;
}
__device__ __forceinline__ uint32_t PKMUL(uint32_t a, uint32_t b) {
  uint32_t d;
  asm("v_pk_mul_f16 %0, %1, %2" : "=v"(d) : "v"(a), "v"(b));
  return d;
}
__device__ __forceinline__ uint32_t PKRELU(uint32_t a) {
  uint32_t d;  // max(a, 0) packed
  asm("v_pk_max_f16 %0, %1, 0" : "=v"(d) : "v"(a));
  return d;
}
__device__ __forceinline__ uint32_t PK(float x, float y) {
  __half2 h = __floats2half2_rn(x, y);
  return *(uint32_t*)&h;
}
__device__ __forceinline__ float CVTLO(uint32_t u) {
  uint16_t t = (uint16_t)(u & 0xffffu);
  __half h = *(__half*)&t;
  return __half2float(h);
}
__device__ __forceinline__ float CVTHI(uint32_t u) {
  uint16_t t = (uint16_t)(u >> 16);
  __half h = *(__half*)&t;
  return __half2float(h);
}
// DPP wave shifts: lane i <- lane i-1 (SHUP) / lane i+1 (SHDN); invalid
// lane gets 0 (bound_ctrl) -- lands in halo contamination zone only.
__device__ __forceinline__ uint32_t SHUP(uint32_t x) {  // wave_shr:1
  return (uint32_t)__builtin_amdgcn_update_dpp(0, (int)x, 0x138, 0xf, 0xf,
                                               true);
}
__device__ __forceinline__ uint32_t SHDN(uint32_t x) {  // wave_shl:1
  return (uint32_t)__builtin_amdgcn_update_dpp(0, (int)x, 0x130, 0xf, 0xf,
                                               true);
}

// One pipeline step: erode (row P <- min-cross of PM,C,N), rolling h-max,
// packed-f16 skel-q update for row K. All indices literal tokens.
#define STEP(P, C, N, DOH, DOU, K, INIT) {                                  \
  const uint32_t ca = F##C##a, cb = F##C##b;                                \
  const uint32_t na = F##N##a, nb = F##N##b;                                \
  const uint32_t vma = HMIN2(HMIN2(PMa, ca), na);                           \
  const uint32_t vmb = HMIN2(HMIN2(PMb, cb), nb);                           \
  const uint32_t t = SHUP(cb);                                              \
  const uint32_t r = SHDN(ca);                                              \
  const uint32_t m1 = mL ? (ca & 0xffffu) : (t >> 16);                      \
  const uint32_t r4 = mR ? (cb >> 16) : (r & 0xffffu);                      \
  const uint32_t sla = (ca >> 16) | (cb << 16);                             \
  const uint32_t slb = (cb >> 16) | (r4 << 16);                             \
  const uint32_t sra = m1 | (ca << 16);                                     \
  const uint32_t ea = HMIN2(vma, HMIN2(sra, sla));                          \
  const uint32_t eb = HMIN2(vmb, HMIN2(sla, slb));                          \
  if (DOH) {                                                                \
    const uint32_t te = SHUP(eb);                                           \
    const uint32_t re = SHDN(ea);                                           \
    const uint32_t em1 = mL ? (ea & 0xffffu) : (te >> 16);                  \
    const uint32_t er4 = mR ? (eb >> 16) : (re & 0xffffu);                  \
    const uint32_t esla = (ea >> 16) | (eb << 16);                          \
    const uint32_t eslb = (eb >> 16) | (er4 << 16);                         \
    const uint32_t esra = em1 | (ea << 16);                                 \
    const uint32_t hca = HMAX2(ea, HMAX2(esra, esla));                      \
    const uint32_t hcb = HMAX2(eb, HMAX2(esla, eslb));                      \
    if (DOU) {                                                              \
      uint32_t haa = h2a, hab = h2b, hba = hca, hbb = hcb;                  \
      if (K == 0 && top) { haa = h1a; hab = h1b; }                          \
      if (K == RV - 1 && bot) { hba = h1a; hbb = h1b; }                     \
      const uint32_t dda = HMAX2(HMAX2(haa, h1a), hba);                     \
      const uint32_t ddb = HMAX2(HMAX2(hab, h1b), hbb);                     \
      const uint32_t fa = PKSUB(ONE2, PKRELU(PKSUB(PMa, dda)));             \
      const uint32_t fb = PKSUB(ONE2, PKRELU(PKSUB(PMb, ddb)));             \
      if (INIT) { Q##K##a = fa; Q##K##b = fb; }                             \
      else { Q##K##a = PKMUL(Q##K##a, fa); Q##K##b = PKMUL(Q##K##b, fb); }  \
    }                                                                       \
    h2a = h1a; h2b = h1b; h1a = hca; h1b = hcb;                             \
  }                                                                         \
  F##P##a = ea; F##P##b = eb;                                               \
  PMa = ca; PMb = cb;                                                       \
}

#define STAGE_BEGIN uint32_t PMa = F0a, PMb = F0b,                          \
    h1a = 0, h1b = 0, h2a = 0, h2b = 0;

// RV=16 stage bodies by valid-row count V; HT = (V-RV-2)/2.
// V=30: HT=6, steps 1..28; DOH [6,23]; DOU [8,23] K=i-8.
#define S_V30(INIT) { STAGE_BEGIN                                           \
  STEP(0,1,2,0,0,0,INIT)   STEP(1,2,3,0,0,0,INIT)   STEP(2,3,4,0,0,0,INIT)  \
  STEP(3,4,5,0,0,0,INIT)   STEP(4,5,6,0,0,0,INIT)                           \
  STEP(5,6,7,1,0,0,INIT)   STEP(6,7,8,1,0,0,INIT)                           \
  STEP(7,8,9,1,1,0,INIT)   STEP(8,9,10,1,1,1,INIT)                          \
  STEP(9,10,11,1,1,2,INIT) STEP(10,11,12,1,1,3,INIT)                        \
  STEP(11,12,13,1,1,4,INIT) STEP(12,13,14,1,1,5,INIT)                       \
  STEP(13,14,15,1,1,6,INIT) STEP(14,15,16,1,1,7,INIT)                       \
  STEP(15,16,17,1,1,8,INIT) STEP(16,17,18,1,1,9,INIT)                       \
  STEP(17,18,19,1,1,10,INIT) STEP(18,19,20,1,1,11,INIT)                     \
  STEP(19,20,21,1,1,12,INIT) STEP(20,21,22,1,1,13,INIT)                     \
  STEP(21,22,23,1,1,14,INIT) STEP(22,23,24,1,1,15,INIT)                     \
  STEP(23,24,25,0,0,0,INIT) STEP(24,25,26,0,0,0,INIT)                       \
  STEP(25,26,27,0,0,0,INIT) STEP(26,27,28,0,0,0,INIT)                       \
  STEP(27,28,29,0,0,0,INIT) }

// V=28: HT=5, steps 1..26; DOH [5,22]; DOU [7,22] K=i-7.
#define S_V28 { STAGE_BEGIN                                                 \
  STEP(0,1,2,0,0,0,0)   STEP(1,2,3,0,0,0,0)   STEP(2,3,4,0,0,0,0)           \
  STEP(3,4,5,0,0,0,0)                                                       \
  STEP(4,5,6,1,0,0,0)   STEP(5,6,7,1,0,0,0)                                 \
  STEP(6,7,8,1,1,0,0)   STEP(7,8,9,1,1,1,0)   STEP(8,9,10,1,1,2,0)          \
  STEP(9,10,11,1,1,3,0) STEP(10,11,12,1,1,4,0) STEP(11,12,13,1,1,5,0)       \
  STEP(12,13,14,1,1,6,0) STEP(13,14,15,1,1,7,0) STEP(14,15,16,1,1,8,0)      \
  STEP(15,16,17,1,1,9,0) STEP(16,17,18,1,1,10,0) STEP(17,18,19,1,1,11,0)    \
  STEP(18,19,20,1,1,12,0) STEP(19,20,21,1,1,13,0) STEP(20,21,22,1,1,14,0)   \
  STEP(21,22,23,1,1,15,0)                                                   \
  STEP(22,23,24,0,0,0,0) STEP(23,24,25,0,0,0,0) STEP(24,25,26,0,0,0,0)      \
  STEP(25,26,27,0,0,0,0) }

// V=26: HT=4, steps 1..24; DOH [4,21]; DOU [6,21] K=i-6.
#define S_V26 { STAGE_BEGIN                                                 \
  STEP(0,1,2,0,0,0,0)   STEP(1,2,3,0,0,0,0)   STEP(2,3,4,0,0,0,0)           \
  STEP(3,4,5,1,0,0,0)   STEP(4,5,6,1,0,0,0)                                 \
  STEP(5,6,7,1,1,0,0)   STEP(6,7,8,1,1,1,0)   STEP(7,8,9,1,1,2,0)           \
  STEP(8,9,10,1,1,3,0)  STEP(9,10,11,1,1,4,0) STEP(10,11,12,1,1,5,0)        \
  STEP(11,12,13,1,1,6,0) STEP(12,13,14,1,1,7,0) STEP(13,14,15,1,1,8,0)      \
  STEP(14,15,16,1,1,9,0) STEP(15,16,17,1,1,10,0) STEP(16,17,18,1,1,11,0)    \
  STEP(17,18,19,1,1,12,0) STEP(18,19,20,1,1,13,0) STEP(19,20,21,1,1,14,0)   \
  STEP(20,21,22,1,1,15,0)                                                   \
  STEP(21,22,23,0,0,0,0) STEP(22,23,24,0,0,0,0) STEP(23,24,25,0,0,0,0) }

// V=24: HT=3, steps 1..22; DOH [3,20]; DOU [5,20] K=i-5.
#define S_V24 { STAGE_BEGIN                                                 \
  STEP(0,1,2,0,0,0,0)   STEP(1,2,3,0,0,0,0)                                 \
  STEP(2,3,4,1,0,0,0)   STEP(3,4,5,1,0,0,0)                                 \
  STEP(4,5,6,1,1,0,0)   STEP(5,6,7,1,1,1,0)   STEP(6,7,8,1,1,2,0)           \
  STEP(7,8,9,1,1,3,0)   STEP(8,9,10,1,1,4,0)  STEP(9,10,11,1,1,5,0)         \
  STEP(10,11,12,1,1,6,0) STEP(11,12,13,1,1,7,0) STEP(12,13,14,1,1,8,0)      \
  STEP(13,14,15,1,1,9,0) STEP(14,15,16,1,1,10,0) STEP(15,16,17,1,1,11,0)    \
  STEP(16,17,18,1,1,12,0) STEP(17,18,19,1,1,13,0) STEP(18,19,20,1,1,14,0)   \
  STEP(19,20,21,1,1,15,0)                                                   \
  STEP(20,21,22,0,0,0,0) STEP(21,22,23,0,0,0,0) }

// V=22: HT=2, steps 1..20; DOH [2,19]; DOU [4,19] K=i-4.
#define S_V22 { STAGE_BEGIN                                                 \
  STEP(0,1,2,0,0,0,0)                                                       \
  STEP(1,2,3,1,0,0,0)   STEP(2,3,4,1,0,0,0)                                 \
  STEP(3,4,5,1,1,0,0)   STEP(4,5,6,1,1,1,0)   STEP(5,6,7,1,1,2,0)           \
  STEP(6,7,8,1,1,3,0)   STEP(7,8,9,1,1,4,0)   STEP(8,9,10,1,1,5,0)          \
  STEP(9,10,11,1,1,6,0) STEP(10,11,12,1,1,7,0) STEP(11,12,13,1,1,8,0)       \
  STEP(12,13,14,1,1,9,0) STEP(13,14,15,1,1,10,0) STEP(14,15,16,1,1,11,0)    \
  STEP(15,16,17,1,1,12,0) STEP(16,17,18,1,1,13,0) STEP(17,18,19,1,1,14,0)   \
  STEP(18,19,20,1,1,15,0)                                                   \
  STEP(19,20,21,0,0,0,0) }

// V=20: HT=1, steps 1..18; DOH [1,18]; DOU [3,18] K=i-3.
#define S_V20 { STAGE_BEGIN                                                 \
  STEP(0,1,2,1,0,0,0)   STEP(1,2,3,1,0,0,0)                                 \
  STEP(2,3,4,1,1,0,0)   STEP(3,4,5,1,1,1,0)   STEP(4,5,6,1,1,2,0)           \
  STEP(5,6,7,1,1,3,0)   STEP(6,7,8,1,1,4,0)   STEP(7,8,9,1,1,5,0)           \
  STEP(8,9,10,1,1,6,0)  STEP(9,10,11,1,1,7,0) STEP(10,11,12,1,1,8,0)        \
  STEP(11,12,13,1,1,9,0) STEP(12,13,14,1,1,10,0) STEP(13,14,15,1,1,11,0)    \
  STEP(14,15,16,1,1,12,0) STEP(15,16,17,1,1,13,0) STEP(16,17,18,1,1,14,0)   \
  STEP(17,18,19,1,1,15,0) }

#define DECLF(i) uint32_t F##i##a, F##i##b;

#define COMMON_SETUP                                                        \
  const int l = threadIdx.x & 63;                                           \
  const int wid = threadIdx.x >> 6;                                         \
  const int w = blockIdx.x;                                                 \
  const int y0 = (blockIdx.y * 2 + wid) * RV;                               \
  const size_t base = (size_t)blockIdx.z * (size_t)(W * H);                 \
  const int rx = 208 * w - 8 + 4 * l;                                       \
  const int cq = min(max(rx, 0), W - 4);                                    \
  const bool mL = (rx == 0);                                                \
  const bool mR = (rx == W - 4);                                            \
  const bool top = (y0 == 0);                                               \
  const bool bot = (y0 + RV == H);                                          \
  const int wend = min(208 * (w + 1), W);                                   \
  const bool wr = (rx >= 208 * w) && (rx < wend);                           \
  const uint32_t ONE2 = 0x3C003C00u;

// Launch 1: stages 1..6 (skel init + iters 1..5); reads img f32, writes
// E6 (f16 packed) + q16 (f16 packed skel complement). HALO=7, R=30.
__global__ __launch_bounds__(128) void skel6(const float* __restrict__ in,
                                             uint16_t* __restrict__ e16,
                                             uint16_t* __restrict__ q16) {
  COMMON_SETUP
  DECLF(0) DECLF(1) DECLF(2) DECLF(3) DECLF(4) DECLF(5) DECLF(6) DECLF(7)
  DECLF(8) DECLF(9) DECLF(10) DECLF(11) DECLF(12) DECLF(13) DECLF(14)
  DECLF(15) DECLF(16) DECLF(17) DECLF(18) DECLF(19) DECLF(20) DECLF(21)
  DECLF(22) DECLF(23) DECLF(24) DECLF(25) DECLF(26) DECLF(27) DECLF(28)
  DECLF(29)
  uint32_t Q0a, Q0b, Q1a, Q1b, Q2a, Q2b, Q3a, Q3b;
  uint32_t Q4a, Q4b, Q5a, Q5b, Q6a, Q6b, Q7a, Q7b;
  uint32_t Q8a, Q8b, Q9a, Q9b, Q10a, Q10b, Q11a, Q11b;
  uint32_t Q12a, Q12b, Q13a, Q13b, Q14a, Q14b, Q15a, Q15b;

#define LOADROW1(i) {                                                       \
    const int gy = min(max(y0 - 7 + i, 0), H - 1);                          \
    const float4 v = *(const float4*)(in + base + (size_t)gy * W + cq);     \
    F##i##a = PK(v.x, v.y); F##i##b = PK(v.z, v.w); }
  LOADROW1(0) LOADROW1(1) LOADROW1(2) LOADROW1(3) LOADROW1(4) LOADROW1(5)
  LOADROW1(6) LOADROW1(7) LOADROW1(8) LOADROW1(9) LOADROW1(10) LOADROW1(11)
  LOADROW1(12) LOADROW1(13) LOADROW1(14) LOADROW1(15) LOADROW1(16)
  LOADROW1(17) LOADROW1(18) LOADROW1(19) LOADROW1(20) LOADROW1(21)
  LOADROW1(22) LOADROW1(23) LOADROW1(24) LOADROW1(25) LOADROW1(26)
  LOADROW1(27) LOADROW1(28) LOADROW1(29)
#undef LOADROW1

  S_V30(1) S_V28 S_V26 S_V24 S_V22 S_V20

  if (wr) {
#define STOREQ(k) {                                                         \
      *(uint2*)(q16 + base + (size_t)(y0 + k) * W + rx) =                   \
          make_uint2(Q##k##a, Q##k##b); }
    STOREQ(0) STOREQ(1) STOREQ(2) STOREQ(3)
    STOREQ(4) STOREQ(5) STOREQ(6) STOREQ(7)
    STOREQ(8) STOREQ(9) STOREQ(10) STOREQ(11)
    STOREQ(12) STOREQ(13) STOREQ(14) STOREQ(15)
#undef STOREQ
    // E6 rows y0+k live in F(1+k) after 6 window shifts.
#define STOREE(k, j) {                                                      \
      *(uint2*)(e16 + base + (size_t)(y0 + k) * W + rx) =                   \
          make_uint2(F##j##a, F##j##b); }
    STOREE(0, 1) STOREE(1, 2) STOREE(2, 3) STOREE(3, 4)
    STOREE(4, 5) STOREE(5, 6) STOREE(6, 7) STOREE(7, 8)
    STOREE(8, 9) STOREE(9, 10) STOREE(10, 11) STOREE(11, 12)
    STOREE(12, 13) STOREE(13, 14) STOREE(14, 15) STOREE(15, 16)
#undef STOREE
  }
}

// Launch 2: stages 7..11 (iters 6..10); reads E6 + q16, writes skel f32.
// HALO=6, R=28.
__global__ __launch_bounds__(128) void skel5(const uint16_t* __restrict__ e16,
                                             const uint16_t* __restrict__ q16,
                                             float* __restrict__ skel) {
  COMMON_SETUP
  DECLF(0) DECLF(1) DECLF(2) DECLF(3) DECLF(4) DECLF(5) DECLF(6) DECLF(7)
  DECLF(8) DECLF(9) DECLF(10) DECLF(11) DECLF(12) DECLF(13) DECLF(14)
  DECLF(15) DECLF(16) DECLF(17) DECLF(18) DECLF(19) DECLF(20) DECLF(21)
  DECLF(22) DECLF(23) DECLF(24) DECLF(25) DECLF(26) DECLF(27)
  uint32_t Q0a, Q0b, Q1a, Q1b, Q2a, Q2b, Q3a, Q3b;
  uint32_t Q4a, Q4b, Q5a, Q5b, Q6a, Q6b, Q7a, Q7b;
  uint32_t Q8a, Q8b, Q9a, Q9b, Q10a, Q10b, Q11a, Q11b;
  uint32_t Q12a, Q12b, Q13a, Q13b, Q14a, Q14b, Q15a, Q15b;

#define LOADROW2(i) {                                                       \
    const int gy = min(max(y0 - 6 + i, 0), H - 1);                          \
    const uint2 v = *(const uint2*)(e16 + base + (size_t)gy * W + cq);      \
    F##i##a = v.x; F##i##b = v.y; }
  LOADROW2(0) LOADROW2(1) LOADROW2(2) LOADROW2(3) LOADROW2(4) LOADROW2(5)
  LOADROW2(6) LOADROW2(7) LOADROW2(8) LOADROW2(9) LOADROW2(10) LOADROW2(11)
  LOADROW2(12) LOADROW2(13) LOADROW2(14) LOADROW2(15) LOADROW2(16)
  LOADROW2(17) LOADROW2(18) LOADROW2(19) LOADROW2(20) LOADROW2(21)
  LOADROW2(22) LOADROW2(23) LOADROW2(24) LOADROW2(25) LOADROW2(26)
  LOADROW2(27)
#undef LOADROW2

#define LOADQ(k) {                                                          \
    const uint2 v = *(const uint2*)(q16 + base + (size_t)(y0 + k) * W + cq); \
    Q##k##a = v.x; Q##k##b = v.y; }
  LOADQ(0) LOADQ(1) LOADQ(2) LOADQ(3) LOADQ(4) LOADQ(5) LOADQ(6) LOADQ(7)
  LOADQ(8) LOADQ(9) LOADQ(10) LOADQ(11) LOADQ(12) LOADQ(13) LOADQ(14)
  LOADQ(15)
#undef LOADQ

  S_V28 S_V26 S_V24 S_V22 S_V20

  if (wr) {
#define STOREQ(k) {                                                         \
      float4 s;                                                             \
      s.x = 1.0f - CVTLO(Q##k##a); s.y = 1.0f - CVTHI(Q##k##a);             \
      s.z = 1.0f - CVTLO(Q##k##b); s.w = 1.0f - CVTHI(Q##k##b);             \
      *(float4*)(skel + base + (size_t)(y0 + k) * W + rx) = s; }
    STOREQ(0) STOREQ(1) STOREQ(2) STOREQ(3)
    STOREQ(4) STOREQ(5) STOREQ(6) STOREQ(7)
    STOREQ(8) STOREQ(9) STOREQ(10) STOREQ(11)
    STOREQ(12) STOREQ(13) STOREQ(14) STOREQ(15)
#undef STOREQ
  }
}

extern "C" void kernel_launch(void* const* d_in, const int* in_sizes, int n_in,
                              void* d_out, int out_size, void* d_ws,
                              size_t ws_size, hipStream_t stream) {
  const float* img = (const float*)d_in[0];
  float* skel = (float*)d_out;
  const size_t NPIX = (size_t)NBATCH * W * H;
  uint16_t* E = (uint16_t*)d_ws;        // 32 MiB f16 E6
  uint16_t* Q = E + NPIX;               // 32 MiB f16 q (skel complement)

  dim3 grid(5, H / (2 * RV), NBATCH);  // 5 x 32 x 16 blocks, 128 thr
  skel6<<<grid, 128, 0, stream>>>(img, E, Q);
  skel5<<<grid, 128, 0, stream>>>(E, Q, skel);
}